// Round 19
// baseline (296.788 us; speedup 1.0000x reference)
//
#include <hip/hip_runtime.h>

// R19: XCD-affinity for the last two kernels. proj64: nc-panel pinned per XCD
// (nc=(bid&7)*2+(j&1)); s1: 80-entry table colocates same-seg (shared-K)
// blocks per XCD residue class. Rest = R18 (296.6us best).

#define L_SEQ 2048
#define NBATCH 4
#define DMODEL 1024
#define NHEAD 8
#define SCALING 0.08838834764831845f
#define NQ (2048L * 4 * 1024)

typedef _Float16 f16x8 __attribute__((ext_vector_type(8)));
typedef float f32x4 __attribute__((ext_vector_type(4)));

#define GLOBAL_AS __attribute__((address_space(1)))
#define LDS_AS __attribute__((address_space(3)))

__device__ __forceinline__ unsigned short f2h_bits(float x) {
  _Float16 h = (_Float16)x;
  return __builtin_bit_cast(unsigned short, h);
}

__device__ __forceinline__ void gl_lds16(const void* g, void* l) {
  __builtin_amdgcn_global_load_lds((GLOBAL_AS void*)g, (LDS_AS void*)l, 16, 0, 0);
}

// s1 (by,seg) table: val = seg*32+by; index = (bid&7)*10 + (bid>>3).
// seg0->xcd0-3, seg1->xcd3-5, seg2->xcd5-7, seg3->xcd7; heavy-by first.
__device__ const unsigned char S1MAP[80] = {
    31, 30, 29, 28, 27, 26, 25, 24, 23, 22,     // xcd0: seg0
    21, 20, 19, 18, 17, 16, 15, 14, 13, 12,     // xcd1: seg0
    11, 10, 9, 8, 7, 6, 5, 4, 3, 2,             // xcd2: seg0
    1, 0, 63, 62, 61, 60, 59, 58, 57, 56,       // xcd3: seg0 tail + seg1
    55, 54, 53, 52, 51, 50, 49, 48, 47, 46,     // xcd4: seg1
    45, 44, 43, 42, 41, 40, 95, 94, 93, 92,     // xcd5: seg1 tail + seg2
    91, 90, 89, 88, 87, 86, 85, 84, 83, 82,     // xcd6: seg2
    81, 80, 127, 126, 125, 124, 123, 122, 121, 120  // xcd7: seg2 tail + seg3
};

// ---------------------------------------------------------------------------
// prep (R18): z<3 transposes; z==3 bias_proj + Zsum zero; z==4 wmean zeros.
// ---------------------------------------------------------------------------
__global__ __launch_bounds__(256) void prep(
    const float* __restrict__ Wq, const float* __restrict__ Wk,
    const float* __restrict__ Wo,
    _Float16* __restrict__ WqT, _Float16* __restrict__ WkT,
    _Float16* __restrict__ WoT,
    const float* __restrict__ bv, float* __restrict__ bvo,
    float4* __restrict__ Zsum4, float* __restrict__ wmean)
{
  const int z = (int)blockIdx.z;
  const int tid = threadIdx.y * 32 + threadIdx.x;
  if (z == 4) {
    int i = blockIdx.y * 32 + blockIdx.x;
    if (i >= 480) return;
    int t = i % 120, nb = i / 120;
    int by = 0, rem = t;
    while (rem >= 15 - by) { rem -= 15 - by; ++by; }
    const int mc = by + 1 + rem;
    const int tr = tid >> 1, th = tid & 1;
    float4 z4 = {0.f, 0.f, 0.f, 0.f};
    float* p = wmean + (long)nb * L_SEQ * L_SEQ + (long)(by * 128 + tr) * L_SEQ +
               mc * 128 + th * 64;
#pragma unroll
    for (int jj = 0; jj < 16; ++jj) ((float4*)p)[jj] = z4;
    return;
  }
  if (z == 3) {
    if (blockIdx.y == 0 && blockIdx.x < 4) {
      int j = blockIdx.x * 256 + tid;
      float acc = 0.f;
      for (int i = 0; i < DMODEL; ++i) acc += bv[i] * Wo[(long)i * DMODEL + j];
      bvo[j] = acc;
    } else if (blockIdx.y == 1 || blockIdx.y == 2) {
      long idx = ((long)(blockIdx.y - 1) * 32 + blockIdx.x) * 256 + tid;
      if (idx < (long)NBATCH * NHEAD * L_SEQ / 4)
        Zsum4[idx] = (float4){0.f, 0.f, 0.f, 0.f};
    }
    return;
  }
  __shared__ _Float16 tile[32][33];
  const float* in = z == 0 ? Wq : (z == 1 ? Wk : Wo);
  _Float16* outp = z == 0 ? WqT : (z == 1 ? WkT : WoT);
  int r0 = blockIdx.y * 32, c0 = blockIdx.x * 32;
  for (int i = threadIdx.y; i < 32; i += 8)
    tile[i][threadIdx.x] = (_Float16)in[(long)(r0 + i) * 1024 + c0 + threadIdx.x];
  __syncthreads();
  for (int i = threadIdx.y; i < 32; i += 8)
    outp[(long)(c0 + i) * 1024 + r0 + threadIdx.x] = tile[threadIdx.x][i];
}

// ---------------------------------------------------------------------------
__global__ __launch_bounds__(256) void cvt3(
    const float* __restrict__ q, const float* __restrict__ k,
    const float* __restrict__ v, _Float16* __restrict__ xh)
{
  long i = ((long)blockIdx.x * 256 + threadIdx.x) * 8;
  if (i >= 3 * NQ) return;
  int which = (int)(i / NQ);
  const float* src = which == 0 ? q : (which == 1 ? k : v);
  long off = i - (long)which * NQ;
  float4 a = *(const float4*)(src + off);
  float4 b = *(const float4*)(src + off + 4);
  f16x8 h;
  h[0] = (_Float16)a.x; h[1] = (_Float16)a.y; h[2] = (_Float16)a.z; h[3] = (_Float16)a.w;
  h[4] = (_Float16)b.x; h[5] = (_Float16)b.y; h[6] = (_Float16)b.z; h[7] = (_Float16)b.w;
  *(f16x8*)(xh + i) = h;
}

// ---------------------------------------------------------------------------
// gemm16: 128x128 tile. Retained for the small Wvo prep GEMM only.
// ---------------------------------------------------------------------------
template <bool AF16, bool BF16>
__global__ __launch_bounds__(256) void gemm16(
    const void* __restrict__ Ap, long lda, long a_bs,
    const void* __restrict__ Bp, long ldb, long b_bs,
    float* __restrict__ C, long ldc, long c_bs,
    _Float16* __restrict__ Ch, long ldch, long ch_bs,
    const float* __restrict__ bias, int bias_row, float alpha, int K,
    int causal, int cmode)
{
  __shared__ __align__(16) _Float16 As[128][64];
  __shared__ __align__(16) _Float16 Bs[128][64];
  const int tid = threadIdx.x;
  const int lane = tid & 63, wv = tid >> 6;
  const int g = lane >> 4, cc = lane & 15;
  const int wm = wv >> 1, wn = wv & 1;
  const long m0 = (long)blockIdx.y * 128;
  const long n0 = (long)blockIdx.x * 128;

  const float* Af = nullptr; const _Float16* Ah = nullptr;
  const float* Bf = nullptr; const _Float16* Bh = nullptr;
  if constexpr (AF16) Ah = (const _Float16*)Ap + (long)blockIdx.z * a_bs;
  else                Af = (const float*)Ap + (long)blockIdx.z * a_bs;
  if constexpr (BF16) Bh = (const _Float16*)Bp + (long)blockIdx.z * b_bs;
  else                Bf = (const float*)Bp + (long)blockIdx.z * b_bs;

  int Keff = K;
  if (causal) { int lim = (int)m0 + 128; if (lim < K) Keff = lim; }
  const int NT = Keff >> 6;

  f32x4 acc[4][4] = {};
  char* AsB = (char*)&As[0][0];
  char* BsB = (char*)&Bs[0][0];

  for (int kt = 0; kt < NT; ++kt) {
    const long k0 = (long)kt << 6;
    __syncthreads();
    if constexpr (AF16) {
#pragma unroll
      for (int i = 0; i < 4; ++i) {
        int r = 32 * wv + 8 * i + (lane >> 3);
        int gc = (lane & 7) ^ (r & 7);
        gl_lds16(Ah + (m0 + r) * lda + k0 + gc * 8, &As[32 * wv + 8 * i][0]);
      }
    } else {
#pragma unroll
      for (int p = 0; p < 8; ++p) {
        int r = p * 16 + (tid >> 4);
        float4 vv = *(const float4*)(Af + (m0 + r) * lda + k0 + (tid & 15) * 4);
        ushort4 hh;
        hh.x = f2h_bits(vv.x); hh.y = f2h_bits(vv.y);
        hh.z = f2h_bits(vv.z); hh.w = f2h_bits(vv.w);
        *(ushort4*)(AsB + r * 128 + (((tid & 15) * 8) ^ ((r & 7) << 4))) = hh;
      }
    }
    if constexpr (BF16) {
#pragma unroll
      for (int i = 0; i < 4; ++i) {
        int r = 32 * wv + 8 * i + (lane >> 3);
        int gc = (lane & 7) ^ (r & 7);
        gl_lds16(Bh + (n0 + r) * ldb + k0 + gc * 8, &Bs[32 * wv + 8 * i][0]);
      }
    } else {
#pragma unroll
      for (int p = 0; p < 8; ++p) {
        int r = p * 16 + (tid >> 4);
        float4 vv = *(const float4*)(Bf + (n0 + r) * ldb + k0 + (tid & 15) * 4);
        ushort4 hh;
        hh.x = f2h_bits(vv.x); hh.y = f2h_bits(vv.y);
        hh.z = f2h_bits(vv.z); hh.w = f2h_bits(vv.w);
        *(ushort4*)(BsB + r * 128 + (((tid & 15) * 8) ^ ((r & 7) << 4))) = hh;
      }
    }
    __syncthreads();
#pragma unroll
    for (int s = 0; s < 2; ++s) {
      f16x8 af[4], bfr[4];
#pragma unroll
      for (int mi = 0; mi < 4; ++mi) {
        int r = wm * 64 + mi * 16 + cc;
        af[mi] = *(const f16x8*)(AsB + r * 128 + ((s * 64 + 16 * g) ^ ((r & 7) << 4)));
      }
#pragma unroll
      for (int ni = 0; ni < 4; ++ni) {
        int r = wn * 64 + ni * 16 + cc;
        bfr[ni] = *(const f16x8*)(BsB + r * 128 + ((s * 64 + 16 * g) ^ ((r & 7) << 4)));
      }
#pragma unroll
      for (int mi = 0; mi < 4; ++mi)
#pragma unroll
        for (int ni = 0; ni < 4; ++ni)
          acc[mi][ni] = __builtin_amdgcn_mfma_f32_16x16x32_f16(af[mi], bfr[ni], acc[mi][ni], 0, 0, 0);
    }
  }

  float* Cp = C ? C + (long)blockIdx.z * c_bs : nullptr;
  _Float16* Chp = Ch ? Ch + (long)blockIdx.z * ch_bs : nullptr;
#pragma unroll
  for (int ni = 0; ni < 4; ++ni) {
    long col = n0 + wn * 64 + ni * 16 + cc;
    float bcol = (bias && !bias_row) ? bias[col] : 0.0f;
#pragma unroll
    for (int mi = 0; mi < 4; ++mi) {
      long row0 = m0 + wm * 64 + mi * 16 + 4 * g;
#pragma unroll
      for (int rg = 0; rg < 4; ++rg) {
        long row = row0 + rg;
        float b = (bias && bias_row) ? bias[row] : bcol;
        float vv = (acc[mi][ni][rg] + b) * alpha;
        if (Cp) Cp[row * ldc + col] = vv;
        if (Chp) {
          if (cmode == 1) {
            long idx = (((row & 3) * NHEAD + (col >> 7)) * (long)L_SEQ + (row >> 2)) * 128 +
                       (col & 127);
            Chp[idx] = (_Float16)vv;
          } else {
            Chp[row * ldch + col] = (_Float16)vv;
          }
        }
      }
    }
  }
}

// ---------------------------------------------------------------------------
// projqk (R17: BK=64 + XCD-affinity).
// ---------------------------------------------------------------------------
__global__ __launch_bounds__(256) void projqk(
    const _Float16* __restrict__ xh, const _Float16* __restrict__ WqT,
    const _Float16* __restrict__ WkT, const float* __restrict__ bq,
    const float* __restrict__ bk, _Float16* __restrict__ qph,
    _Float16* __restrict__ kph)
{
  __shared__ __align__(16) _Float16 As[64][64];
  __shared__ __align__(16) _Float16 Bs[128][64];
  const int tid = threadIdx.x, lane = tid & 63, wv = tid >> 6;
  const int g = lane >> 4, cc = lane & 15;
  const int wm = wv >> 1, wn = wv & 1;
  const int sel = (int)blockIdx.y;
  const _Float16* A = xh + (long)sel * NQ;
  const _Float16* B = sel ? WkT : WqT;
  const float* bias = sel ? bk : bq;
  const float alpha = sel ? 1.0f : SCALING;
  _Float16* dst = sel ? kph : qph;
  const int bid = (int)blockIdx.x;
  const int j = bid >> 3;
  const int mt = (bid & 7) * 16 + (j & 15);
  const int nt = j >> 4;
  const long m0 = (long)mt * 64;
  const long n0 = (long)nt * 128;

  f32x4 acc[2][4] = {};
  char* AsB = (char*)&As[0][0];
  char* BsB = (char*)&Bs[0][0];

  for (int kt = 0; kt < 16; ++kt) {
    const long k0 = (long)kt << 6;
    __syncthreads();
#pragma unroll
    for (int i = 0; i < 2; ++i) {
      int r = 16 * wv + 8 * i + (lane >> 3);
      int gc = (lane & 7) ^ (r & 7);
      gl_lds16(A + (m0 + r) * 1024 + k0 + gc * 8, &As[16 * wv + 8 * i][0]);
    }
#pragma unroll
    for (int i = 0; i < 4; ++i) {
      int r = 32 * wv + 8 * i + (lane >> 3);
      int gc = (lane & 7) ^ (r & 7);
      gl_lds16(B + (n0 + r) * 1024 + k0 + gc * 8, &Bs[32 * wv + 8 * i][0]);
    }
    __syncthreads();
#pragma unroll
    for (int s = 0; s < 2; ++s) {
      f16x8 af[2], bfr[4];
#pragma unroll
      for (int mi = 0; mi < 2; ++mi) {
        int r = wm * 32 + mi * 16 + cc;
        af[mi] = *(const f16x8*)(AsB + r * 128 + ((s * 64 + 16 * g) ^ ((r & 7) << 4)));
      }
#pragma unroll
      for (int ni = 0; ni < 4; ++ni) {
        int r = wn * 64 + ni * 16 + cc;
        bfr[ni] = *(const f16x8*)(BsB + r * 128 + ((s * 64 + 16 * g) ^ ((r & 7) << 4)));
      }
#pragma unroll
      for (int mi = 0; mi < 2; ++mi)
#pragma unroll
        for (int ni = 0; ni < 4; ++ni)
          acc[mi][ni] = __builtin_amdgcn_mfma_f32_16x16x32_f16(af[mi], bfr[ni], acc[mi][ni], 0, 0, 0);
    }
  }

#pragma unroll
  for (int ni = 0; ni < 4; ++ni) {
    long col = n0 + wn * 64 + ni * 16 + cc;
    float bcol = bias[col];
#pragma unroll
    for (int mi = 0; mi < 2; ++mi) {
      long row0 = m0 + wm * 32 + mi * 16 + 4 * g;
#pragma unroll
      for (int rg = 0; rg < 4; ++rg) {
        long row = row0 + rg;
        float vv = (acc[mi][ni][rg] + bcol) * alpha;
        long idx = (((row & 3) * NHEAD + (col >> 7)) * (long)L_SEQ + (row >> 2)) * 128 +
                   (col & 127);
        dst[idx] = (_Float16)vv;
      }
    }
  }
}

// ---------------------------------------------------------------------------
// proj64 (voT; + XCD-affinity): nc = (bid&7)*2 + (j&1), by = j>>1 —
// B-panel pairs pinned per XCD (2MB working set); A (WvoT, 2MB) broadcast.
// ---------------------------------------------------------------------------
__global__ __launch_bounds__(256) void proj64(
    const _Float16* __restrict__ Ap, long lda, long a_bs,
    const _Float16* __restrict__ Bp, long ldb, long b_bs,
    _Float16* __restrict__ Ch, long ldch, long ch_bs,
    const float* __restrict__ bias, int bias_row, float alpha, int K,
    int cmode, int ntiles)
{
  __shared__ __align__(16) _Float16 As[64][64];
  __shared__ __align__(16) _Float16 Bs[128][64];
  const int tid = threadIdx.x, lane = tid & 63, wv = tid >> 6;
  const int g = lane >> 4, cc = lane & 15;
  const int wm = wv >> 1, wn = wv & 1;
  const int bid = (int)blockIdx.x;
  const int j = bid >> 3;
  const int nc = (bid & 7) * 2 + (j & 1);   // B-panel pinned to XCD bid&7
  const int by = j >> 1;
  const long m0 = (long)by * 64;
  const long n0 = (long)nc * 128;
  const _Float16* A = Ap + (long)blockIdx.z * a_bs;
  const _Float16* B = Bp + (long)blockIdx.z * b_bs;
  const int NT = K >> 6;

  f32x4 acc[2][4] = {};
  char* AsB = (char*)&As[0][0];
  char* BsB = (char*)&Bs[0][0];

  for (int kt = 0; kt < NT; ++kt) {
    const long k0 = (long)kt << 6;
    __syncthreads();
#pragma unroll
    for (int i = 0; i < 2; ++i) {
      int r = 16 * wv + 8 * i + (lane >> 3);
      int gc = (lane & 7) ^ (r & 7);
      gl_lds16(A + (m0 + r) * lda + k0 + gc * 8, &As[16 * wv + 8 * i][0]);
    }
#pragma unroll
    for (int i = 0; i < 4; ++i) {
      int r = 32 * wv + 8 * i + (lane >> 3);
      int gc = (lane & 7) ^ (r & 7);
      gl_lds16(B + (n0 + r) * ldb + k0 + gc * 8, &Bs[32 * wv + 8 * i][0]);
    }
    __syncthreads();
#pragma unroll
    for (int s = 0; s < 2; ++s) {
      f16x8 af[2], bfr[4];
#pragma unroll
      for (int mi = 0; mi < 2; ++mi) {
        int r = wm * 32 + mi * 16 + cc;
        af[mi] = *(const f16x8*)(AsB + r * 128 + ((s * 64 + 16 * g) ^ ((r & 7) << 4)));
      }
#pragma unroll
      for (int ni = 0; ni < 4; ++ni) {
        int r = wn * 64 + ni * 16 + cc;
        bfr[ni] = *(const f16x8*)(BsB + r * 128 + ((s * 64 + 16 * g) ^ ((r & 7) << 4)));
      }
#pragma unroll
      for (int mi = 0; mi < 2; ++mi)
#pragma unroll
        for (int ni = 0; ni < 4; ++ni)
          acc[mi][ni] = __builtin_amdgcn_mfma_f32_16x16x32_f16(af[mi], bfr[ni], acc[mi][ni], 0, 0, 0);
    }
  }

  _Float16* Chp = Ch + (long)blockIdx.z * ch_bs;
#pragma unroll
  for (int ni = 0; ni < 4; ++ni) {
    long col = n0 + wn * 64 + ni * 16 + cc;
    float bcol = bias_row ? 0.0f : bias[col];
#pragma unroll
    for (int mi = 0; mi < 2; ++mi) {
      long row0 = m0 + wm * 32 + mi * 16 + 4 * g;
#pragma unroll
      for (int rg = 0; rg < 4; ++rg) {
        long row = row0 + rg;
        float b = bias_row ? bias[row] : bcol;
        float vv = (acc[mi][ni][rg] + b) * alpha;
        if (cmode == 1) {
          long idx = (((row & 3) * NHEAD + (col >> 7)) * (long)L_SEQ + (row >> 2)) * 128 +
                     (col & 127);
          Chp[idx] = (_Float16)vv;
        } else {
          Chp[row * ldch + col] = (_Float16)vv;
        }
      }
    }
  }
}

// ---------------------------------------------------------------------------
// out_gemm16 (R17: BK=128 + XCD-affinity).
// ---------------------------------------------------------------------------
__global__ __launch_bounds__(256) void out_gemm16(
    const _Float16* __restrict__ wm16, const _Float16* __restrict__ voT,
    const float* __restrict__ bo, float* __restrict__ out)
{
  __shared__ __align__(16) _Float16 As[64][128];
  __shared__ __align__(16) _Float16 Bs[128][128];
  const int tid = threadIdx.x, lane = tid & 63, wv = tid >> 6;
  const int g = lane >> 4, cc = lane & 15;
  const int wm = wv >> 1, wn = wv & 1;
  const int bid = (int)blockIdx.x;
  const int j = bid >> 3;
  const int p = (j >> 3) * 8 + (bid & 7);
  const int by = 31 - (p >> 2);
  const int nb = p & 3;
  const int nc = j & 7;
  const long m0 = (long)by * 64;
  const long n0 = (long)nc * 128;
  const _Float16* A = wm16 + (long)nb * L_SEQ * L_SEQ;
  const _Float16* B = voT + (long)nb * 2048L * 1024;
  const int NT = (by + 2) >> 1;
  const int srow = lane >> 4, scl = lane & 15;

  f32x4 acc[2][4] = {};
  char* AsB = (char*)&As[0][0];
  char* BsB = (char*)&Bs[0][0];

  for (int kt = 0; kt < NT; ++kt) {
    const long k0 = (long)kt << 7;
    __syncthreads();
#pragma unroll
    for (int i = 0; i < 4; ++i) {
      int r = 16 * wv + 4 * i + srow;
      int gc = scl ^ (r & 7);
      gl_lds16(A + (m0 + r) * 2048 + k0 + gc * 8, &As[16 * wv + 4 * i][0]);
    }
#pragma unroll
    for (int i = 0; i < 8; ++i) {
      int r = 32 * wv + 4 * i + srow;
      int gc = scl ^ (r & 7);
      gl_lds16(B + (n0 + r) * 2048 + k0 + gc * 8, &Bs[32 * wv + 4 * i][0]);
    }
    __syncthreads();
#pragma unroll
    for (int s = 0; s < 4; ++s) {
      f16x8 af[2], bfr[4];
#pragma unroll
      for (int mi = 0; mi < 2; ++mi) {
        int r = wm * 32 + mi * 16 + cc;
        af[mi] = *(const f16x8*)(AsB + r * 256 + (((4 * s + g) ^ (r & 7)) << 4));
      }
#pragma unroll
      for (int ni = 0; ni < 4; ++ni) {
        int r = wn * 64 + ni * 16 + cc;
        bfr[ni] = *(const f16x8*)(BsB + r * 256 + (((4 * s + g) ^ (r & 7)) << 4));
      }
#pragma unroll
      for (int mi = 0; mi < 2; ++mi)
#pragma unroll
        for (int ni = 0; ni < 4; ++ni)
          acc[mi][ni] = __builtin_amdgcn_mfma_f32_16x16x32_f16(af[mi], bfr[ni], acc[mi][ni], 0, 0, 0);
    }
  }

#pragma unroll
  for (int ni = 0; ni < 4; ++ni) {
    long col = n0 + wn * 64 + ni * 16 + cc;
    float b = bo[col];
#pragma unroll
    for (int mi = 0; mi < 2; ++mi) {
      long l0 = m0 + wm * 32 + mi * 16 + 4 * g;
#pragma unroll
      for (int rg = 0; rg < 4; ++rg)
        out[(l0 + rg) * 4096 + nb * 1024 + col] = acc[mi][ni][rg] + b;
    }
  }
}

// ---------------------------------------------------------------------------
// S1 (R10 + seg-affinity table): same-seg (shared-K) blocks colocated per
// XCD residue class via S1MAP.
// ---------------------------------------------------------------------------
__global__ __launch_bounds__(256) void s1_kernel(
    const _Float16* __restrict__ qph, const _Float16* __restrict__ kph,
    float* __restrict__ Zsum)
{
  __shared__ __align__(16) _Float16 Qs[64][128];
  __shared__ __align__(16) _Float16 Ks[64][128];
  const int tid = threadIdx.x, lane = tid & 63, w = tid >> 6;
  const int g = lane >> 4, cc = lane & 15;
  const int h = blockIdx.y, nb = blockIdx.z;
  const int bid = (int)blockIdx.x;
  const int val = S1MAP[(bid & 7) * 10 + (bid >> 3)];
  const int by = val & 31, seg = val >> 5;
  const int lb = by * 64;
  const int c0 = seg * 8;
  const int cEnd = min(c0 + 8, by + 1);
  const int srow = lane >> 4, scl = lane & 15;
  const long hb = ((long)(nb * NHEAD + h)) * L_SEQ * 128;
  char* QsB = (char*)&Qs[0][0];
  char* KsB = (char*)&Ks[0][0];

#pragma unroll
  for (int i = 0; i < 4; ++i) {
    int r = 16 * w + 4 * i + srow;
    int gc = scl ^ (r & 7);
    gl_lds16(&qph[hb + (long)(lb + r) * 128 + gc * 8], &Qs[16 * w + 4 * i][0]);
  }
  auto stageK = [&](int ch) {
#pragma unroll
    for (int i = 0; i < 4; ++i) {
      int r = 16 * w + 4 * i + srow;
      int gc = scl ^ (r & 7);
      gl_lds16(&kph[hb + (long)(ch * 64 + r) * 128 + gc * 8], &Ks[16 * w + 4 * i][0]);
    }
  };
  stageK(c0);
  __syncthreads();

  f16x8 qf[4];
  {
    int r = 16 * w + cc;
#pragma unroll
    for (int s = 0; s < 4; ++s)
      qf[s] = *(const f16x8*)(QsB + r * 256 + ((64 * s + 16 * g) ^ ((r & 7) << 4)));
  }

  f32x4 zacc = {0.f, 0.f, 0.f, 0.f};
  const int l0 = lb + 16 * w + 4 * g;
  for (int ch = c0; ch < cEnd; ++ch) {
#pragma unroll
    for (int t = 0; t < 4; ++t) {
      int kr = 16 * t + cc;
      f32x4 acc = {0.f, 0.f, 0.f, 0.f};
#pragma unroll
      for (int s = 0; s < 4; ++s) {
        f16x8 kf = *(const f16x8*)(KsB + kr * 256 + ((64 * s + 16 * g) ^ ((kr & 7) << 4)));
        acc = __builtin_amdgcn_mfma_f32_16x16x32_f16(qf[s], kf, acc, 0, 0, 0);
      }
      int m = ch * 64 + 16 * t + cc;
#pragma unroll
      for (int rg = 0; rg < 4; ++rg) {
        float e = __expf(acc[rg]);
        zacc[rg] += (m <= l0 + rg) ? e : 0.f;
      }
    }
    if (ch + 1 < cEnd) {
      __syncthreads();
      stageK(ch + 1);
      __syncthreads();
    }
  }
#pragma unroll
  for (int rg = 0; rg < 4; ++rg) {
    float vv = zacc[rg];
    vv += __shfl_xor(vv, 1, 16);
    vv += __shfl_xor(vv, 2, 16);
    vv += __shfl_xor(vv, 4, 16);
    vv += __shfl_xor(vv, 8, 16);
    if (cc == 0)
      atomicAdd(&Zsum[((long)nb * NHEAD + h) * L_SEQ + l0 + rg], vv);
  }
}

// ---------------------------------------------------------------------------
// S2 (R18, proven): 64l x 128m tiles + mc-pair XCD-affinity.
// ---------------------------------------------------------------------------
__global__ __launch_bounds__(256) void s2_kernel(
    const _Float16* __restrict__ qph, const _Float16* __restrict__ kph,
    const float* __restrict__ Zsum, float* __restrict__ wmean,
    _Float16* __restrict__ wm16)
{
  __shared__ __align__(16) _Float16 Qs[64][128];
  __shared__ __align__(16) _Float16 Ks[128][128];
  __shared__ float zl[NHEAD][64];
  const int tid = threadIdx.x, lane = tid & 63, w = tid >> 6;
  const int g = lane >> 4, cc = lane & 15;
  const int nb = blockIdx.y;
  const int x = (int)blockIdx.x;
  const int xcd = x & 7, idx = x >> 3;
  const int cnt0 = 32 - 2 * xcd;
  int mc, by;
  if (idx < cnt0) { mc = xcd;      by = 31 - idx; }
  else            { mc = 15 - xcd; by = 31 - (idx - cnt0); }
  const int lb = by * 64, mb = mc * 128;
  const bool diag = (mb + 127 > lb);
  const int srow = lane >> 4, scl = lane & 15;
  char* QsB = (char*)&Qs[0][0];
  char* KsB = (char*)&Ks[0][0];

  for (int i = tid; i < NHEAD * 64; i += 256)
    zl[i >> 6][i & 63] =
        1.0f / (8.0f * Zsum[((long)nb * NHEAD + (i >> 6)) * L_SEQ + lb + (i & 63)]);

  auto stage = [&](int h) {
    const long qb = ((long)(nb * NHEAD + h) * L_SEQ + lb) * 128;
    const long kb = ((long)(nb * NHEAD + h) * L_SEQ + mb) * 128;
#pragma unroll
    for (int i = 0; i < 4; ++i) {
      int r = 16 * w + 4 * i + srow;
      int gc = scl ^ (r & 7);
      gl_lds16(&qph[qb + (long)r * 128 + gc * 8], &Qs[16 * w + 4 * i][0]);
    }
#pragma unroll
    for (int i = 0; i < 8; ++i) {
      int r = 32 * w + 4 * i + srow;
      int gc = scl ^ (r & 7);
      gl_lds16(&kph[kb + (long)r * 128 + gc * 8], &Ks[32 * w + 4 * i][0]);
    }
  };
  stage(0);
  __syncthreads();

  f32x4 wacc[8] = {};
  const int l0 = lb + 16 * w + 4 * g;
  for (int h = 0; h < NHEAD; ++h) {
    f16x8 qf[4];
    int qr = 16 * w + cc;
#pragma unroll
    for (int s = 0; s < 4; ++s)
      qf[s] = *(const f16x8*)(QsB + qr * 256 + ((64 * s + 16 * g) ^ ((qr & 7) << 4)));
    f32x4 zv = *(const f32x4*)&zl[h][16 * w + 4 * g];
#pragma unroll
    for (int t = 0; t < 8; ++t) {
      int kr = 16 * t + cc;
      f32x4 acc = {0.f, 0.f, 0.f, 0.f};
#pragma unroll
      for (int s = 0; s < 4; ++s) {
        f16x8 kf = *(const f16x8*)(KsB + kr * 256 + ((64 * s + 16 * g) ^ ((kr & 7) << 4)));
        acc = __builtin_amdgcn_mfma_f32_16x16x32_f16(qf[s], kf, acc, 0, 0, 0);
      }
      int m = mb + 16 * t + cc;
#pragma unroll
      for (int rg = 0; rg < 4; ++rg) {
        float e = __expf(acc[rg]) * zv[rg];
        wacc[t][rg] += (!diag || m <= l0 + rg) ? e : 0.f;
      }
    }
    if (h + 1 < NHEAD) {
      __syncthreads();
      stage(h + 1);
      __syncthreads();
    }
  }
  float* wout = wmean + (long)nb * L_SEQ * L_SEQ;
  _Float16* w16 = wm16 + (long)nb * L_SEQ * L_SEQ;
#pragma unroll
  for (int t = 0; t < 8; ++t) {
    int m = mb + 16 * t + cc;
#pragma unroll
    for (int rg = 0; rg < 4; ++rg) {
      long idx2 = (long)(l0 + rg) * L_SEQ + m;
      wout[idx2] = wacc[t][rg];
      w16[idx2] = (_Float16)wacc[t][rg];
    }
  }
}

// ---------------------------------------------------------------------------
extern "C" void kernel_launch(void* const* d_in, const int* in_sizes, int n_in,
                              void* d_out, int out_size, void* d_ws, size_t ws_size,
                              hipStream_t stream)
{
  const float* q  = (const float*)d_in[0];
  const float* k  = (const float*)d_in[1];
  const float* v  = (const float*)d_in[2];
  const float* Wq = (const float*)d_in[3];
  const float* bq = (const float*)d_in[4];
  const float* Wk = (const float*)d_in[5];
  const float* bk = (const float*)d_in[6];
  const float* Wv = (const float*)d_in[7];
  const float* bv = (const float*)d_in[8];
  const float* Wo = (const float*)d_in[9];
  const float* bo = (const float*)d_in[10];

  float* out = (float*)d_out;
  float* wmean = out + (long)L_SEQ * NBATCH * DMODEL;

  if (ws_size < (140UL << 20)) return;

  char* ws = (char*)d_ws;
  _Float16* xh   = (_Float16*)(ws);                   // 48 MB (q,k,v f16)
  _Float16* qph  = (_Float16*)(ws + (48L << 20));     // 16 MB head-major
  _Float16* kph  = (_Float16*)(ws + (64L << 20));     // 16 MB head-major
  _Float16* voT  = (_Float16*)(ws + (80L << 20));     // 16 MB
  _Float16* wm16 = (_Float16*)(ws + (96L << 20));     // 33.6 MB (f16 wmean)
  _Float16* WqT  = (_Float16*)(ws + (130L << 20));    // 2 MB
  _Float16* WkT  = (_Float16*)(ws + (132L << 20));    // 2 MB
  _Float16* WoT  = (_Float16*)(ws + (134L << 20));    // 2 MB
  _Float16* WvoT = (_Float16*)(ws + (136L << 20));    // 2 MB
  float*    bvo  = (float*)   (ws + (138L << 20));    // 4 KB
  float*    Zsum = (float*)   (ws + (138L << 20) + (1L << 16));  // 256 KB

  prep<<<dim3(32, 32, 5), dim3(32, 8, 1), 0, stream>>>(
      Wq, Wk, Wo, WqT, WkT, WoT, bv, bvo, (float4*)Zsum, wmean);
  gemm16<true, false><<<dim3(8, 8, 1), 256, 0, stream>>>(
      WoT, 1024, 0, Wv, 1024, 0,
      (float*)nullptr, 0, 0, WvoT, 1024, 0,
      (const float*)nullptr, 0, 1.0f, 1024, 0, 0);
  cvt3<<<dim3(12288, 1, 1), 256, 0, stream>>>(q, k, v, xh);
  projqk<<<dim3(1024, 2, 1), 256, 0, stream>>>(xh, WqT, WkT, bq, bk, qph, kph);
  proj64<<<dim3(256, 1, 4), 256, 0, stream>>>(
      WvoT, 1024, 0, xh + 2 * NQ, 4096, 1024, voT, 2048, 2048L * 1024,
      bvo, 1, 1.0f, 1024, 0, 16);
  s1_kernel<<<dim3(80, NHEAD, NBATCH), 256, 0, stream>>>(qph, kph, Zsum);
  s2_kernel<<<dim3(272, NBATCH, 1), 256, 0, stream>>>(qph, kph, Zsum, wmean, wm16);
  out_gemm16<<<dim3(1024, 1, 1), 256, 0, stream>>>(wm16, voT, bo, out);
}

// Round 20
// 286.531 us; speedup vs baseline: 1.0358x; 1.0358x over previous
//
#include <hip/hip_runtime.h>

// R20 (final): cvt3 folded into prep as z=5..16 (dependency-free; exact
// 12x1024x256x8 = 3*NQ coverage) — one fewer launch, better packing of the
// small prep planes. All else = R19 (296.7us best).
//
// Session summary (430 -> ~293us): f16 MFMA everywhere; algebraic Wvo fold;
// head-major layouts; gl_lds staging (never register-streaming: R7);
// TLP-first (4 blocks/CU beats dbuf: R3/R9); K-split when partial output is
// tiny (s1: R10) but never via mass atomics (out: R11); BK=128 only for
// 128B-conflict-free layouts... empirically 256B-row swizzle conflicts
// (R15/R16); XCD-affinity where FETCH >> compulsory (R17/R18).

#define L_SEQ 2048
#define NBATCH 4
#define DMODEL 1024
#define NHEAD 8
#define SCALING 0.08838834764831845f
#define NQ (2048L * 4 * 1024)

typedef _Float16 f16x8 __attribute__((ext_vector_type(8)));
typedef float f32x4 __attribute__((ext_vector_type(4)));

#define GLOBAL_AS __attribute__((address_space(1)))
#define LDS_AS __attribute__((address_space(3)))

__device__ __forceinline__ unsigned short f2h_bits(float x) {
  _Float16 h = (_Float16)x;
  return __builtin_bit_cast(unsigned short, h);
}

__device__ __forceinline__ void gl_lds16(const void* g, void* l) {
  __builtin_amdgcn_global_load_lds((GLOBAL_AS void*)g, (LDS_AS void*)l, 16, 0, 0);
}

// s1 (by,seg) table: val = seg*32+by; index = (bid&7)*10 + (bid>>3).
__device__ const unsigned char S1MAP[80] = {
    31, 30, 29, 28, 27, 26, 25, 24, 23, 22,
    21, 20, 19, 18, 17, 16, 15, 14, 13, 12,
    11, 10, 9, 8, 7, 6, 5, 4, 3, 2,
    1, 0, 63, 62, 61, 60, 59, 58, 57, 56,
    55, 54, 53, 52, 51, 50, 49, 48, 47, 46,
    45, 44, 43, 42, 41, 40, 95, 94, 93, 92,
    91, 90, 89, 88, 87, 86, 85, 84, 83, 82,
    81, 80, 127, 126, 125, 124, 123, 122, 121, 120
};

// ---------------------------------------------------------------------------
// prep: z<3 weight transposes; z==3 bias_proj + Zsum zero; z==4 wmean
// strict-upper zeros; z=5..16 f32->f16 cvt of q,k,v into xh (fused cvt3).
// ---------------------------------------------------------------------------
__global__ __launch_bounds__(256) void prep(
    const float* __restrict__ Wq, const float* __restrict__ Wk,
    const float* __restrict__ Wo,
    _Float16* __restrict__ WqT, _Float16* __restrict__ WkT,
    _Float16* __restrict__ WoT,
    const float* __restrict__ bv, float* __restrict__ bvo,
    float4* __restrict__ Zsum4, float* __restrict__ wmean,
    const float* __restrict__ q, const float* __restrict__ k,
    const float* __restrict__ v, _Float16* __restrict__ xh)
{
  const int z = (int)blockIdx.z;
  const int tid = threadIdx.y * 32 + threadIdx.x;
  if (z >= 5) {                              // fused cvt3: xh = f16(q,k,v)
    long blk = (long)(z - 5) * 1024 + blockIdx.y * 32 + blockIdx.x;
    long i = (blk * 256 + tid) * 8;
    int which = (int)(i / NQ);
    const float* src = which == 0 ? q : (which == 1 ? k : v);
    long off = i - (long)which * NQ;
    float4 a = *(const float4*)(src + off);
    float4 b = *(const float4*)(src + off + 4);
    f16x8 h;
    h[0] = (_Float16)a.x; h[1] = (_Float16)a.y; h[2] = (_Float16)a.z; h[3] = (_Float16)a.w;
    h[4] = (_Float16)b.x; h[5] = (_Float16)b.y; h[6] = (_Float16)b.z; h[7] = (_Float16)b.w;
    *(f16x8*)(xh + i) = h;
    return;
  }
  if (z == 4) {                              // wmean strict-upper zeros
    int i = blockIdx.y * 32 + blockIdx.x;
    if (i >= 480) return;
    int t = i % 120, nb = i / 120;
    int by = 0, rem = t;
    while (rem >= 15 - by) { rem -= 15 - by; ++by; }
    const int mc = by + 1 + rem;
    const int tr = tid >> 1, th = tid & 1;
    float4 z4 = {0.f, 0.f, 0.f, 0.f};
    float* p = wmean + (long)nb * L_SEQ * L_SEQ + (long)(by * 128 + tr) * L_SEQ +
               mc * 128 + th * 64;
#pragma unroll
    for (int jj = 0; jj < 16; ++jj) ((float4*)p)[jj] = z4;
    return;
  }
  if (z == 3) {
    if (blockIdx.y == 0 && blockIdx.x < 4) {
      int j = blockIdx.x * 256 + tid;
      float acc = 0.f;
      for (int i = 0; i < DMODEL; ++i) acc += bv[i] * Wo[(long)i * DMODEL + j];
      bvo[j] = acc;
    } else if (blockIdx.y == 1 || blockIdx.y == 2) {
      long idx = ((long)(blockIdx.y - 1) * 32 + blockIdx.x) * 256 + tid;
      if (idx < (long)NBATCH * NHEAD * L_SEQ / 4)
        Zsum4[idx] = (float4){0.f, 0.f, 0.f, 0.f};
    }
    return;
  }
  __shared__ _Float16 tile[32][33];
  const float* in = z == 0 ? Wq : (z == 1 ? Wk : Wo);
  _Float16* outp = z == 0 ? WqT : (z == 1 ? WkT : WoT);
  int r0 = blockIdx.y * 32, c0 = blockIdx.x * 32;
  for (int i = threadIdx.y; i < 32; i += 8)
    tile[i][threadIdx.x] = (_Float16)in[(long)(r0 + i) * 1024 + c0 + threadIdx.x];
  __syncthreads();
  for (int i = threadIdx.y; i < 32; i += 8)
    outp[(long)(c0 + i) * 1024 + r0 + threadIdx.x] = tile[threadIdx.x][i];
}

// ---------------------------------------------------------------------------
// gemm16: 128x128 tile. Retained for the small Wvo prep GEMM only.
// ---------------------------------------------------------------------------
template <bool AF16, bool BF16>
__global__ __launch_bounds__(256) void gemm16(
    const void* __restrict__ Ap, long lda, long a_bs,
    const void* __restrict__ Bp, long ldb, long b_bs,
    float* __restrict__ C, long ldc, long c_bs,
    _Float16* __restrict__ Ch, long ldch, long ch_bs,
    const float* __restrict__ bias, int bias_row, float alpha, int K,
    int causal, int cmode)
{
  __shared__ __align__(16) _Float16 As[128][64];
  __shared__ __align__(16) _Float16 Bs[128][64];
  const int tid = threadIdx.x;
  const int lane = tid & 63, wv = tid >> 6;
  const int g = lane >> 4, cc = lane & 15;
  const int wm = wv >> 1, wn = wv & 1;
  const long m0 = (long)blockIdx.y * 128;
  const long n0 = (long)blockIdx.x * 128;

  const float* Af = nullptr; const _Float16* Ah = nullptr;
  const float* Bf = nullptr; const _Float16* Bh = nullptr;
  if constexpr (AF16) Ah = (const _Float16*)Ap + (long)blockIdx.z * a_bs;
  else                Af = (const float*)Ap + (long)blockIdx.z * a_bs;
  if constexpr (BF16) Bh = (const _Float16*)Bp + (long)blockIdx.z * b_bs;
  else                Bf = (const float*)Bp + (long)blockIdx.z * b_bs;

  int Keff = K;
  if (causal) { int lim = (int)m0 + 128; if (lim < K) Keff = lim; }
  const int NT = Keff >> 6;

  f32x4 acc[4][4] = {};
  char* AsB = (char*)&As[0][0];
  char* BsB = (char*)&Bs[0][0];

  for (int kt = 0; kt < NT; ++kt) {
    const long k0 = (long)kt << 6;
    __syncthreads();
    if constexpr (AF16) {
#pragma unroll
      for (int i = 0; i < 4; ++i) {
        int r = 32 * wv + 8 * i + (lane >> 3);
        int gc = (lane & 7) ^ (r & 7);
        gl_lds16(Ah + (m0 + r) * lda + k0 + gc * 8, &As[32 * wv + 8 * i][0]);
      }
    } else {
#pragma unroll
      for (int p = 0; p < 8; ++p) {
        int r = p * 16 + (tid >> 4);
        float4 vv = *(const float4*)(Af + (m0 + r) * lda + k0 + (tid & 15) * 4);
        ushort4 hh;
        hh.x = f2h_bits(vv.x); hh.y = f2h_bits(vv.y);
        hh.z = f2h_bits(vv.z); hh.w = f2h_bits(vv.w);
        *(ushort4*)(AsB + r * 128 + (((tid & 15) * 8) ^ ((r & 7) << 4))) = hh;
      }
    }
    if constexpr (BF16) {
#pragma unroll
      for (int i = 0; i < 4; ++i) {
        int r = 32 * wv + 8 * i + (lane >> 3);
        int gc = (lane & 7) ^ (r & 7);
        gl_lds16(Bh + (n0 + r) * ldb + k0 + gc * 8, &Bs[32 * wv + 8 * i][0]);
      }
    } else {
#pragma unroll
      for (int p = 0; p < 8; ++p) {
        int r = p * 16 + (tid >> 4);
        float4 vv = *(const float4*)(Bf + (n0 + r) * ldb + k0 + (tid & 15) * 4);
        ushort4 hh;
        hh.x = f2h_bits(vv.x); hh.y = f2h_bits(vv.y);
        hh.z = f2h_bits(vv.z); hh.w = f2h_bits(vv.w);
        *(ushort4*)(BsB + r * 128 + (((tid & 15) * 8) ^ ((r & 7) << 4))) = hh;
      }
    }
    __syncthreads();
#pragma unroll
    for (int s = 0; s < 2; ++s) {
      f16x8 af[4], bfr[4];
#pragma unroll
      for (int mi = 0; mi < 4; ++mi) {
        int r = wm * 64 + mi * 16 + cc;
        af[mi] = *(const f16x8*)(AsB + r * 128 + ((s * 64 + 16 * g) ^ ((r & 7) << 4)));
      }
#pragma unroll
      for (int ni = 0; ni < 4; ++ni) {
        int r = wn * 64 + ni * 16 + cc;
        bfr[ni] = *(const f16x8*)(BsB + r * 128 + ((s * 64 + 16 * g) ^ ((r & 7) << 4)));
      }
#pragma unroll
      for (int mi = 0; mi < 4; ++mi)
#pragma unroll
        for (int ni = 0; ni < 4; ++ni)
          acc[mi][ni] = __builtin_amdgcn_mfma_f32_16x16x32_f16(af[mi], bfr[ni], acc[mi][ni], 0, 0, 0);
    }
  }

  float* Cp = C ? C + (long)blockIdx.z * c_bs : nullptr;
  _Float16* Chp = Ch ? Ch + (long)blockIdx.z * ch_bs : nullptr;
#pragma unroll
  for (int ni = 0; ni < 4; ++ni) {
    long col = n0 + wn * 64 + ni * 16 + cc;
    float bcol = (bias && !bias_row) ? bias[col] : 0.0f;
#pragma unroll
    for (int mi = 0; mi < 4; ++mi) {
      long row0 = m0 + wm * 64 + mi * 16 + 4 * g;
#pragma unroll
      for (int rg = 0; rg < 4; ++rg) {
        long row = row0 + rg;
        float b = (bias && bias_row) ? bias[row] : bcol;
        float vv = (acc[mi][ni][rg] + b) * alpha;
        if (Cp) Cp[row * ldc + col] = vv;
        if (Chp) {
          if (cmode == 1) {
            long idx = (((row & 3) * NHEAD + (col >> 7)) * (long)L_SEQ + (row >> 2)) * 128 +
                       (col & 127);
            Chp[idx] = (_Float16)vv;
          } else {
            Chp[row * ldch + col] = (_Float16)vv;
          }
        }
      }
    }
  }
}

// ---------------------------------------------------------------------------
// projqk (R17: BK=64 + XCD-affinity).
// ---------------------------------------------------------------------------
__global__ __launch_bounds__(256) void projqk(
    const _Float16* __restrict__ xh, const _Float16* __restrict__ WqT,
    const _Float16* __restrict__ WkT, const float* __restrict__ bq,
    const float* __restrict__ bk, _Float16* __restrict__ qph,
    _Float16* __restrict__ kph)
{
  __shared__ __align__(16) _Float16 As[64][64];
  __shared__ __align__(16) _Float16 Bs[128][64];
  const int tid = threadIdx.x, lane = tid & 63, wv = tid >> 6;
  const int g = lane >> 4, cc = lane & 15;
  const int wm = wv >> 1, wn = wv & 1;
  const int sel = (int)blockIdx.y;
  const _Float16* A = xh + (long)sel * NQ;
  const _Float16* B = sel ? WkT : WqT;
  const float* bias = sel ? bk : bq;
  const float alpha = sel ? 1.0f : SCALING;
  _Float16* dst = sel ? kph : qph;
  const int bid = (int)blockIdx.x;
  const int j = bid >> 3;
  const int mt = (bid & 7) * 16 + (j & 15);
  const int nt = j >> 4;
  const long m0 = (long)mt * 64;
  const long n0 = (long)nt * 128;

  f32x4 acc[2][4] = {};
  char* AsB = (char*)&As[0][0];
  char* BsB = (char*)&Bs[0][0];

  for (int kt = 0; kt < 16; ++kt) {
    const long k0 = (long)kt << 6;
    __syncthreads();
#pragma unroll
    for (int i = 0; i < 2; ++i) {
      int r = 16 * wv + 8 * i + (lane >> 3);
      int gc = (lane & 7) ^ (r & 7);
      gl_lds16(A + (m0 + r) * 1024 + k0 + gc * 8, &As[16 * wv + 8 * i][0]);
    }
#pragma unroll
    for (int i = 0; i < 4; ++i) {
      int r = 32 * wv + 8 * i + (lane >> 3);
      int gc = (lane & 7) ^ (r & 7);
      gl_lds16(B + (n0 + r) * 1024 + k0 + gc * 8, &Bs[32 * wv + 8 * i][0]);
    }
    __syncthreads();
#pragma unroll
    for (int s = 0; s < 2; ++s) {
      f16x8 af[2], bfr[4];
#pragma unroll
      for (int mi = 0; mi < 2; ++mi) {
        int r = wm * 32 + mi * 16 + cc;
        af[mi] = *(const f16x8*)(AsB + r * 128 + ((s * 64 + 16 * g) ^ ((r & 7) << 4)));
      }
#pragma unroll
      for (int ni = 0; ni < 4; ++ni) {
        int r = wn * 64 + ni * 16 + cc;
        bfr[ni] = *(const f16x8*)(BsB + r * 128 + ((s * 64 + 16 * g) ^ ((r & 7) << 4)));
      }
#pragma unroll
      for (int mi = 0; mi < 2; ++mi)
#pragma unroll
        for (int ni = 0; ni < 4; ++ni)
          acc[mi][ni] = __builtin_amdgcn_mfma_f32_16x16x32_f16(af[mi], bfr[ni], acc[mi][ni], 0, 0, 0);
    }
  }

#pragma unroll
  for (int ni = 0; ni < 4; ++ni) {
    long col = n0 + wn * 64 + ni * 16 + cc;
    float bcol = bias[col];
#pragma unroll
    for (int mi = 0; mi < 2; ++mi) {
      long row0 = m0 + wm * 32 + mi * 16 + 4 * g;
#pragma unroll
      for (int rg = 0; rg < 4; ++rg) {
        long row = row0 + rg;
        float vv = (acc[mi][ni][rg] + bcol) * alpha;
        long idx = (((row & 3) * NHEAD + (col >> 7)) * (long)L_SEQ + (row >> 2)) * 128 +
                   (col & 127);
        dst[idx] = (_Float16)vv;
      }
    }
  }
}

// ---------------------------------------------------------------------------
// proj64 (R19: voT, nc-panel XCD-affinity).
// ---------------------------------------------------------------------------
__global__ __launch_bounds__(256) void proj64(
    const _Float16* __restrict__ Ap, long lda, long a_bs,
    const _Float16* __restrict__ Bp, long ldb, long b_bs,
    _Float16* __restrict__ Ch, long ldch, long ch_bs,
    const float* __restrict__ bias, int bias_row, float alpha, int K,
    int cmode, int ntiles)
{
  __shared__ __align__(16) _Float16 As[64][64];
  __shared__ __align__(16) _Float16 Bs[128][64];
  const int tid = threadIdx.x, lane = tid & 63, wv = tid >> 6;
  const int g = lane >> 4, cc = lane & 15;
  const int wm = wv >> 1, wn = wv & 1;
  const int bid = (int)blockIdx.x;
  const int j = bid >> 3;
  const int nc = (bid & 7) * 2 + (j & 1);
  const int by = j >> 1;
  const long m0 = (long)by * 64;
  const long n0 = (long)nc * 128;
  const _Float16* A = Ap + (long)blockIdx.z * a_bs;
  const _Float16* B = Bp + (long)blockIdx.z * b_bs;
  const int NT = K >> 6;

  f32x4 acc[2][4] = {};
  char* AsB = (char*)&As[0][0];
  char* BsB = (char*)&Bs[0][0];

  for (int kt = 0; kt < NT; ++kt) {
    const long k0 = (long)kt << 6;
    __syncthreads();
#pragma unroll
    for (int i = 0; i < 2; ++i) {
      int r = 16 * wv + 8 * i + (lane >> 3);
      int gc = (lane & 7) ^ (r & 7);
      gl_lds16(A + (m0 + r) * lda + k0 + gc * 8, &As[16 * wv + 8 * i][0]);
    }
#pragma unroll
    for (int i = 0; i < 4; ++i) {
      int r = 32 * wv + 8 * i + (lane >> 3);
      int gc = (lane & 7) ^ (r & 7);
      gl_lds16(B + (n0 + r) * ldb + k0 + gc * 8, &Bs[32 * wv + 8 * i][0]);
    }
    __syncthreads();
#pragma unroll
    for (int s = 0; s < 2; ++s) {
      f16x8 af[2], bfr[4];
#pragma unroll
      for (int mi = 0; mi < 2; ++mi) {
        int r = wm * 32 + mi * 16 + cc;
        af[mi] = *(const f16x8*)(AsB + r * 128 + ((s * 64 + 16 * g) ^ ((r & 7) << 4)));
      }
#pragma unroll
      for (int ni = 0; ni < 4; ++ni) {
        int r = wn * 64 + ni * 16 + cc;
        bfr[ni] = *(const f16x8*)(BsB + r * 128 + ((s * 64 + 16 * g) ^ ((r & 7) << 4)));
      }
#pragma unroll
      for (int mi = 0; mi < 2; ++mi)
#pragma unroll
        for (int ni = 0; ni < 4; ++ni)
          acc[mi][ni] = __builtin_amdgcn_mfma_f32_16x16x32_f16(af[mi], bfr[ni], acc[mi][ni], 0, 0, 0);
    }
  }

  _Float16* Chp = Ch + (long)blockIdx.z * ch_bs;
#pragma unroll
  for (int ni = 0; ni < 4; ++ni) {
    long col = n0 + wn * 64 + ni * 16 + cc;
    float bcol = bias_row ? 0.0f : bias[col];
#pragma unroll
    for (int mi = 0; mi < 2; ++mi) {
      long row0 = m0 + wm * 32 + mi * 16 + 4 * g;
#pragma unroll
      for (int rg = 0; rg < 4; ++rg) {
        long row = row0 + rg;
        float b = bias_row ? bias[row] : bcol;
        float vv = (acc[mi][ni][rg] + b) * alpha;
        if (cmode == 1) {
          long idx = (((row & 3) * NHEAD + (col >> 7)) * (long)L_SEQ + (row >> 2)) * 128 +
                     (col & 127);
          Chp[idx] = (_Float16)vv;
        } else {
          Chp[row * ldch + col] = (_Float16)vv;
        }
      }
    }
  }
}

// ---------------------------------------------------------------------------
// out_gemm16 (R17: BK=128 + XCD-affinity).
// ---------------------------------------------------------------------------
__global__ __launch_bounds__(256) void out_gemm16(
    const _Float16* __restrict__ wm16, const _Float16* __restrict__ voT,
    const float* __restrict__ bo, float* __restrict__ out)
{
  __shared__ __align__(16) _Float16 As[64][128];
  __shared__ __align__(16) _Float16 Bs[128][128];
  const int tid = threadIdx.x, lane = tid & 63, wv = tid >> 6;
  const int g = lane >> 4, cc = lane & 15;
  const int wm = wv >> 1, wn = wv & 1;
  const int bid = (int)blockIdx.x;
  const int j = bid >> 3;
  const int p = (j >> 3) * 8 + (bid & 7);
  const int by = 31 - (p >> 2);
  const int nb = p & 3;
  const int nc = j & 7;
  const long m0 = (long)by * 64;
  const long n0 = (long)nc * 128;
  const _Float16* A = wm16 + (long)nb * L_SEQ * L_SEQ;
  const _Float16* B = voT + (long)nb * 2048L * 1024;
  const int NT = (by + 2) >> 1;
  const int srow = lane >> 4, scl = lane & 15;

  f32x4 acc[2][4] = {};
  char* AsB = (char*)&As[0][0];
  char* BsB = (char*)&Bs[0][0];

  for (int kt = 0; kt < NT; ++kt) {
    const long k0 = (long)kt << 7;
    __syncthreads();
#pragma unroll
    for (int i = 0; i < 4; ++i) {
      int r = 16 * wv + 4 * i + srow;
      int gc = scl ^ (r & 7);
      gl_lds16(A + (m0 + r) * 2048 + k0 + gc * 8, &As[16 * wv + 4 * i][0]);
    }
#pragma unroll
    for (int i = 0; i < 8; ++i) {
      int r = 32 * wv + 4 * i + srow;
      int gc = scl ^ (r & 7);
      gl_lds16(B + (n0 + r) * 2048 + k0 + gc * 8, &Bs[32 * wv + 4 * i][0]);
    }
    __syncthreads();
#pragma unroll
    for (int s = 0; s < 4; ++s) {
      f16x8 af[2], bfr[4];
#pragma unroll
      for (int mi = 0; mi < 2; ++mi) {
        int r = wm * 32 + mi * 16 + cc;
        af[mi] = *(const f16x8*)(AsB + r * 256 + (((4 * s + g) ^ (r & 7)) << 4));
      }
#pragma unroll
      for (int ni = 0; ni < 4; ++ni) {
        int r = wn * 64 + ni * 16 + cc;
        bfr[ni] = *(const f16x8*)(BsB + r * 256 + (((4 * s + g) ^ (r & 7)) << 4));
      }
#pragma unroll
      for (int mi = 0; mi < 2; ++mi)
#pragma unroll
        for (int ni = 0; ni < 4; ++ni)
          acc[mi][ni] = __builtin_amdgcn_mfma_f32_16x16x32_f16(af[mi], bfr[ni], acc[mi][ni], 0, 0, 0);
    }
  }

#pragma unroll
  for (int ni = 0; ni < 4; ++ni) {
    long col = n0 + wn * 64 + ni * 16 + cc;
    float b = bo[col];
#pragma unroll
    for (int mi = 0; mi < 2; ++mi) {
      long l0 = m0 + wm * 32 + mi * 16 + 4 * g;
#pragma unroll
      for (int rg = 0; rg < 4; ++rg)
        out[(l0 + rg) * 4096 + nb * 1024 + col] = acc[mi][ni][rg] + b;
    }
  }
}

// ---------------------------------------------------------------------------
// S1 (R19): K-split partial Zsum, seg-affinity table.
// ---------------------------------------------------------------------------
__global__ __launch_bounds__(256) void s1_kernel(
    const _Float16* __restrict__ qph, const _Float16* __restrict__ kph,
    float* __restrict__ Zsum)
{
  __shared__ __align__(16) _Float16 Qs[64][128];
  __shared__ __align__(16) _Float16 Ks[64][128];
  const int tid = threadIdx.x, lane = tid & 63, w = tid >> 6;
  const int g = lane >> 4, cc = lane & 15;
  const int h = blockIdx.y, nb = blockIdx.z;
  const int bid = (int)blockIdx.x;
  const int val = S1MAP[(bid & 7) * 10 + (bid >> 3)];
  const int by = val & 31, seg = val >> 5;
  const int lb = by * 64;
  const int c0 = seg * 8;
  const int cEnd = min(c0 + 8, by + 1);
  const int srow = lane >> 4, scl = lane & 15;
  const long hb = ((long)(nb * NHEAD + h)) * L_SEQ * 128;
  char* QsB = (char*)&Qs[0][0];
  char* KsB = (char*)&Ks[0][0];

#pragma unroll
  for (int i = 0; i < 4; ++i) {
    int r = 16 * w + 4 * i + srow;
    int gc = scl ^ (r & 7);
    gl_lds16(&qph[hb + (long)(lb + r) * 128 + gc * 8], &Qs[16 * w + 4 * i][0]);
  }
  auto stageK = [&](int ch) {
#pragma unroll
    for (int i = 0; i < 4; ++i) {
      int r = 16 * w + 4 * i + srow;
      int gc = scl ^ (r & 7);
      gl_lds16(&kph[hb + (long)(ch * 64 + r) * 128 + gc * 8], &Ks[16 * w + 4 * i][0]);
    }
  };
  stageK(c0);
  __syncthreads();

  f16x8 qf[4];
  {
    int r = 16 * w + cc;
#pragma unroll
    for (int s = 0; s < 4; ++s)
      qf[s] = *(const f16x8*)(QsB + r * 256 + ((64 * s + 16 * g) ^ ((r & 7) << 4)));
  }

  f32x4 zacc = {0.f, 0.f, 0.f, 0.f};
  const int l0 = lb + 16 * w + 4 * g;
  for (int ch = c0; ch < cEnd; ++ch) {
#pragma unroll
    for (int t = 0; t < 4; ++t) {
      int kr = 16 * t + cc;
      f32x4 acc = {0.f, 0.f, 0.f, 0.f};
#pragma unroll
      for (int s = 0; s < 4; ++s) {
        f16x8 kf = *(const f16x8*)(KsB + kr * 256 + ((64 * s + 16 * g) ^ ((kr & 7) << 4)));
        acc = __builtin_amdgcn_mfma_f32_16x16x32_f16(qf[s], kf, acc, 0, 0, 0);
      }
      int m = ch * 64 + 16 * t + cc;
#pragma unroll
      for (int rg = 0; rg < 4; ++rg) {
        float e = __expf(acc[rg]);
        zacc[rg] += (m <= l0 + rg) ? e : 0.f;
      }
    }
    if (ch + 1 < cEnd) {
      __syncthreads();
      stageK(ch + 1);
      __syncthreads();
    }
  }
#pragma unroll
  for (int rg = 0; rg < 4; ++rg) {
    float vv = zacc[rg];
    vv += __shfl_xor(vv, 1, 16);
    vv += __shfl_xor(vv, 2, 16);
    vv += __shfl_xor(vv, 4, 16);
    vv += __shfl_xor(vv, 8, 16);
    if (cc == 0)
      atomicAdd(&Zsum[((long)nb * NHEAD + h) * L_SEQ + l0 + rg], vv);
  }
}

// ---------------------------------------------------------------------------
// S2 (R18): 64l x 128m tiles + mc-pair XCD-affinity.
// ---------------------------------------------------------------------------
__global__ __launch_bounds__(256) void s2_kernel(
    const _Float16* __restrict__ qph, const _Float16* __restrict__ kph,
    const float* __restrict__ Zsum, float* __restrict__ wmean,
    _Float16* __restrict__ wm16)
{
  __shared__ __align__(16) _Float16 Qs[64][128];
  __shared__ __align__(16) _Float16 Ks[128][128];
  __shared__ float zl[NHEAD][64];
  const int tid = threadIdx.x, lane = tid & 63, w = tid >> 6;
  const int g = lane >> 4, cc = lane & 15;
  const int nb = blockIdx.y;
  const int x = (int)blockIdx.x;
  const int xcd = x & 7, idx = x >> 3;
  const int cnt0 = 32 - 2 * xcd;
  int mc, by;
  if (idx < cnt0) { mc = xcd;      by = 31 - idx; }
  else            { mc = 15 - xcd; by = 31 - (idx - cnt0); }
  const int lb = by * 64, mb = mc * 128;
  const bool diag = (mb + 127 > lb);
  const int srow = lane >> 4, scl = lane & 15;
  char* QsB = (char*)&Qs[0][0];
  char* KsB = (char*)&Ks[0][0];

  for (int i = tid; i < NHEAD * 64; i += 256)
    zl[i >> 6][i & 63] =
        1.0f / (8.0f * Zsum[((long)nb * NHEAD + (i >> 6)) * L_SEQ + lb + (i & 63)]);

  auto stage = [&](int h) {
    const long qb = ((long)(nb * NHEAD + h) * L_SEQ + lb) * 128;
    const long kb = ((long)(nb * NHEAD + h) * L_SEQ + mb) * 128;
#pragma unroll
    for (int i = 0; i < 4; ++i) {
      int r = 16 * w + 4 * i + srow;
      int gc = scl ^ (r & 7);
      gl_lds16(&qph[qb + (long)r * 128 + gc * 8], &Qs[16 * w + 4 * i][0]);
    }
#pragma unroll
    for (int i = 0; i < 8; ++i) {
      int r = 32 * w + 4 * i + srow;
      int gc = scl ^ (r & 7);
      gl_lds16(&kph[kb + (long)r * 128 + gc * 8], &Ks[32 * w + 4 * i][0]);
    }
  };
  stage(0);
  __syncthreads();

  f32x4 wacc[8] = {};
  const int l0 = lb + 16 * w + 4 * g;
  for (int h = 0; h < NHEAD; ++h) {
    f16x8 qf[4];
    int qr = 16 * w + cc;
#pragma unroll
    for (int s = 0; s < 4; ++s)
      qf[s] = *(const f16x8*)(QsB + qr * 256 + ((64 * s + 16 * g) ^ ((qr & 7) << 4)));
    f32x4 zv = *(const f32x4*)&zl[h][16 * w + 4 * g];
#pragma unroll
    for (int t = 0; t < 8; ++t) {
      int kr = 16 * t + cc;
      f32x4 acc = {0.f, 0.f, 0.f, 0.f};
#pragma unroll
      for (int s = 0; s < 4; ++s) {
        f16x8 kf = *(const f16x8*)(KsB + kr * 256 + ((64 * s + 16 * g) ^ ((kr & 7) << 4)));
        acc = __builtin_amdgcn_mfma_f32_16x16x32_f16(qf[s], kf, acc, 0, 0, 0);
      }
      int m = mb + 16 * t + cc;
#pragma unroll
      for (int rg = 0; rg < 4; ++rg) {
        float e = __expf(acc[rg]) * zv[rg];
        wacc[t][rg] += (!diag || m <= l0 + rg) ? e : 0.f;
      }
    }
    if (h + 1 < NHEAD) {
      __syncthreads();
      stage(h + 1);
      __syncthreads();
    }
  }
  float* wout = wmean + (long)nb * L_SEQ * L_SEQ;
  _Float16* w16 = wm16 + (long)nb * L_SEQ * L_SEQ;
#pragma unroll
  for (int t = 0; t < 8; ++t) {
    int m = mb + 16 * t + cc;
#pragma unroll
    for (int rg = 0; rg < 4; ++rg) {
      long idx2 = (long)(l0 + rg) * L_SEQ + m;
      wout[idx2] = wacc[t][rg];
      w16[idx2] = (_Float16)wacc[t][rg];
    }
  }
}

// ---------------------------------------------------------------------------
extern "C" void kernel_launch(void* const* d_in, const int* in_sizes, int n_in,
                              void* d_out, int out_size, void* d_ws, size_t ws_size,
                              hipStream_t stream)
{
  const float* q  = (const float*)d_in[0];
  const float* k  = (const float*)d_in[1];
  const float* v  = (const float*)d_in[2];
  const float* Wq = (const float*)d_in[3];
  const float* bq = (const float*)d_in[4];
  const float* Wk = (const float*)d_in[5];
  const float* bk = (const float*)d_in[6];
  const float* Wv = (const float*)d_in[7];
  const float* bv = (const float*)d_in[8];
  const float* Wo = (const float*)d_in[9];
  const float* bo = (const float*)d_in[10];

  float* out = (float*)d_out;
  float* wmean = out + (long)L_SEQ * NBATCH * DMODEL;

  if (ws_size < (140UL << 20)) return;

  char* ws = (char*)d_ws;
  _Float16* xh   = (_Float16*)(ws);                   // 48 MB (q,k,v f16)
  _Float16* qph  = (_Float16*)(ws + (48L << 20));     // 16 MB head-major
  _Float16* kph  = (_Float16*)(ws + (64L << 20));     // 16 MB head-major
  _Float16* voT  = (_Float16*)(ws + (80L << 20));     // 16 MB
  _Float16* wm16 = (_Float16*)(ws + (96L << 20));     // 33.6 MB (f16 wmean)
  _Float16* WqT  = (_Float16*)(ws + (130L << 20));    // 2 MB
  _Float16* WkT  = (_Float16*)(ws + (132L << 20));    // 2 MB
  _Float16* WoT  = (_Float16*)(ws + (134L << 20));    // 2 MB
  _Float16* WvoT = (_Float16*)(ws + (136L << 20));    // 2 MB
  float*    bvo  = (float*)   (ws + (138L << 20));    // 4 KB
  float*    Zsum = (float*)   (ws + (138L << 20) + (1L << 16));  // 256 KB

  // transposes + bias_proj + Zsum zero + wmean zeros + cvt3, one launch
  prep<<<dim3(32, 32, 17), dim3(32, 8, 1), 0, stream>>>(
      Wq, Wk, Wo, WqT, WkT, WoT, bv, bvo, (float4*)Zsum, wmean, q, k, v, xh);
  gemm16<true, false><<<dim3(8, 8, 1), 256, 0, stream>>>(
      WoT, 1024, 0, Wv, 1024, 0,
      (float*)nullptr, 0, 0, WvoT, 1024, 0,
      (const float*)nullptr, 0, 1.0f, 1024, 0, 0);
  projqk<<<dim3(1024, 2, 1), 256, 0, stream>>>(xh, WqT, WkT, bq, bk, qph, kph);
  proj64<<<dim3(256, 1, 4), 256, 0, stream>>>(
      WvoT, 1024, 0, xh + 2 * NQ, 4096, 1024, voT, 2048, 2048L * 1024,
      bvo, 1, 1.0f, 1024, 0, 16);
  s1_kernel<<<dim3(80, NHEAD, NBATCH), 256, 0, stream>>>(qph, kph, Zsum);
  s2_kernel<<<dim3(272, NBATCH, 1), 256, 0, stream>>>(qph, kph, Zsum, wmean, wm16);
  out_gemm16<<<dim3(1024, 1, 1), 256, 0, stream>>>(wm16, voT, bo, out);
}

// Round 21
// 275.132 us; speedup vs baseline: 1.0787x; 1.0414x over previous
//
#include <hip/hip_runtime.h>

// R21: prep restructured — (1) bias_proj parallelized (32 blocks, 8-way
// i-split + LDS reduce; was a 1024-deep serial load chain on 4 blocks,
// ~50-60us hidden tail); (2) plane reorder: cvt first (z=0..11) so the
// 150MB BW work dispatches ahead of the small planes. Rest = R20 (286.5us).

#define L_SEQ 2048
#define NBATCH 4
#define DMODEL 1024
#define NHEAD 8
#define SCALING 0.08838834764831845f
#define NQ (2048L * 4 * 1024)

typedef _Float16 f16x8 __attribute__((ext_vector_type(8)));
typedef float f32x4 __attribute__((ext_vector_type(4)));

#define GLOBAL_AS __attribute__((address_space(1)))
#define LDS_AS __attribute__((address_space(3)))

__device__ __forceinline__ unsigned short f2h_bits(float x) {
  _Float16 h = (_Float16)x;
  return __builtin_bit_cast(unsigned short, h);
}

__device__ __forceinline__ void gl_lds16(const void* g, void* l) {
  __builtin_amdgcn_global_load_lds((GLOBAL_AS void*)g, (LDS_AS void*)l, 16, 0, 0);
}

// s1 (by,seg) table: val = seg*32+by; index = (bid&7)*10 + (bid>>3).
__device__ const unsigned char S1MAP[80] = {
    31, 30, 29, 28, 27, 26, 25, 24, 23, 22,
    21, 20, 19, 18, 17, 16, 15, 14, 13, 12,
    11, 10, 9, 8, 7, 6, 5, 4, 3, 2,
    1, 0, 63, 62, 61, 60, 59, 58, 57, 56,
    55, 54, 53, 52, 51, 50, 49, 48, 47, 46,
    45, 44, 43, 42, 41, 40, 95, 94, 93, 92,
    91, 90, 89, 88, 87, 86, 85, 84, 83, 82,
    81, 80, 127, 126, 125, 124, 123, 122, 121, 120
};

// ---------------------------------------------------------------------------
// prep: z=0..11 cvt3 (q,k,v f32->f16, BW work FIRST in dispatch order);
// z=12..14 weight transposes; z=15 parallel bias_proj (y==0) + Zsum zero
// (y==1,2); z=16 wmean strict-upper zeros.
// ---------------------------------------------------------------------------
__global__ __launch_bounds__(256) void prep(
    const float* __restrict__ Wq, const float* __restrict__ Wk,
    const float* __restrict__ Wo,
    _Float16* __restrict__ WqT, _Float16* __restrict__ WkT,
    _Float16* __restrict__ WoT,
    const float* __restrict__ bv, float* __restrict__ bvo,
    float4* __restrict__ Zsum4, float* __restrict__ wmean,
    const float* __restrict__ q, const float* __restrict__ k,
    const float* __restrict__ v, _Float16* __restrict__ xh)
{
  const int z = (int)blockIdx.z;
  const int tid = threadIdx.y * 32 + threadIdx.x;
  if (z < 12) {                              // cvt3: xh = f16(q,k,v)
    long blk = (long)z * 1024 + blockIdx.y * 32 + blockIdx.x;
    long i = (blk * 256 + tid) * 8;
    int which = (int)(i / NQ);
    const float* src = which == 0 ? q : (which == 1 ? k : v);
    long off = i - (long)which * NQ;
    float4 a = *(const float4*)(src + off);
    float4 b = *(const float4*)(src + off + 4);
    f16x8 h;
    h[0] = (_Float16)a.x; h[1] = (_Float16)a.y; h[2] = (_Float16)a.z; h[3] = (_Float16)a.w;
    h[4] = (_Float16)b.x; h[5] = (_Float16)b.y; h[6] = (_Float16)b.z; h[7] = (_Float16)b.w;
    *(f16x8*)(xh + i) = h;
    return;
  }
  if (z < 15) {                              // weight transposes
    __shared__ _Float16 tile[32][33];
    const int zz = z - 12;
    const float* in = zz == 0 ? Wq : (zz == 1 ? Wk : Wo);
    _Float16* outp = zz == 0 ? WqT : (zz == 1 ? WkT : WoT);
    int r0 = blockIdx.y * 32, c0 = blockIdx.x * 32;
    for (int i = threadIdx.y; i < 32; i += 8)
      tile[i][threadIdx.x] = (_Float16)in[(long)(r0 + i) * 1024 + c0 + threadIdx.x];
    __syncthreads();
    for (int i = threadIdx.y; i < 32; i += 8)
      outp[(long)(c0 + i) * 1024 + r0 + threadIdx.x] = tile[threadIdx.x][i];
    return;
  }
  if (z == 15) {
    if (blockIdx.y == 0) {                   // parallel bias_proj (32 blocks)
      __shared__ float red[8][32];
      const int j = blockIdx.x * 32 + (tid & 31);
      const int i0 = (tid >> 5) * 128;
      float acc = 0.f;
#pragma unroll 4
      for (int i = 0; i < 128; ++i)
        acc += bv[i0 + i] * Wo[(long)(i0 + i) * 1024 + j];
      red[tid >> 5][tid & 31] = acc;
      __syncthreads();
      if (tid < 32) {
        float s = 0.f;
#pragma unroll
        for (int r = 0; r < 8; ++r) s += red[r][tid];
        bvo[blockIdx.x * 32 + tid] = s;
      }
    } else if (blockIdx.y == 1 || blockIdx.y == 2) {  // Zsum zero
      long idx = ((long)(blockIdx.y - 1) * 32 + blockIdx.x) * 256 + tid;
      if (idx < (long)NBATCH * NHEAD * L_SEQ / 4)
        Zsum4[idx] = (float4){0.f, 0.f, 0.f, 0.f};
    }
    return;
  }
  // z == 16: wmean strict-upper zeros
  int i = blockIdx.y * 32 + blockIdx.x;
  if (i >= 480) return;
  int t = i % 120, nb = i / 120;
  int by = 0, rem = t;
  while (rem >= 15 - by) { rem -= 15 - by; ++by; }
  const int mc = by + 1 + rem;
  const int tr = tid >> 1, th = tid & 1;
  float4 z4 = {0.f, 0.f, 0.f, 0.f};
  float* p = wmean + (long)nb * L_SEQ * L_SEQ + (long)(by * 128 + tr) * L_SEQ +
             mc * 128 + th * 64;
#pragma unroll
  for (int jj = 0; jj < 16; ++jj) ((float4*)p)[jj] = z4;
}

// ---------------------------------------------------------------------------
// gemm16: 128x128 tile. Retained for the small Wvo prep GEMM only.
// ---------------------------------------------------------------------------
template <bool AF16, bool BF16>
__global__ __launch_bounds__(256) void gemm16(
    const void* __restrict__ Ap, long lda, long a_bs,
    const void* __restrict__ Bp, long ldb, long b_bs,
    float* __restrict__ C, long ldc, long c_bs,
    _Float16* __restrict__ Ch, long ldch, long ch_bs,
    const float* __restrict__ bias, int bias_row, float alpha, int K,
    int causal, int cmode)
{
  __shared__ __align__(16) _Float16 As[128][64];
  __shared__ __align__(16) _Float16 Bs[128][64];
  const int tid = threadIdx.x;
  const int lane = tid & 63, wv = tid >> 6;
  const int g = lane >> 4, cc = lane & 15;
  const int wm = wv >> 1, wn = wv & 1;
  const long m0 = (long)blockIdx.y * 128;
  const long n0 = (long)blockIdx.x * 128;

  const float* Af = nullptr; const _Float16* Ah = nullptr;
  const float* Bf = nullptr; const _Float16* Bh = nullptr;
  if constexpr (AF16) Ah = (const _Float16*)Ap + (long)blockIdx.z * a_bs;
  else                Af = (const float*)Ap + (long)blockIdx.z * a_bs;
  if constexpr (BF16) Bh = (const _Float16*)Bp + (long)blockIdx.z * b_bs;
  else                Bf = (const float*)Bp + (long)blockIdx.z * b_bs;

  int Keff = K;
  if (causal) { int lim = (int)m0 + 128; if (lim < K) Keff = lim; }
  const int NT = Keff >> 6;

  f32x4 acc[4][4] = {};
  char* AsB = (char*)&As[0][0];
  char* BsB = (char*)&Bs[0][0];

  for (int kt = 0; kt < NT; ++kt) {
    const long k0 = (long)kt << 6;
    __syncthreads();
    if constexpr (AF16) {
#pragma unroll
      for (int i = 0; i < 4; ++i) {
        int r = 32 * wv + 8 * i + (lane >> 3);
        int gc = (lane & 7) ^ (r & 7);
        gl_lds16(Ah + (m0 + r) * lda + k0 + gc * 8, &As[32 * wv + 8 * i][0]);
      }
    } else {
#pragma unroll
      for (int p = 0; p < 8; ++p) {
        int r = p * 16 + (tid >> 4);
        float4 vv = *(const float4*)(Af + (m0 + r) * lda + k0 + (tid & 15) * 4);
        ushort4 hh;
        hh.x = f2h_bits(vv.x); hh.y = f2h_bits(vv.y);
        hh.z = f2h_bits(vv.z); hh.w = f2h_bits(vv.w);
        *(ushort4*)(AsB + r * 128 + (((tid & 15) * 8) ^ ((r & 7) << 4))) = hh;
      }
    }
    if constexpr (BF16) {
#pragma unroll
      for (int i = 0; i < 4; ++i) {
        int r = 32 * wv + 8 * i + (lane >> 3);
        int gc = (lane & 7) ^ (r & 7);
        gl_lds16(Bh + (n0 + r) * ldb + k0 + gc * 8, &Bs[32 * wv + 8 * i][0]);
      }
    } else {
#pragma unroll
      for (int p = 0; p < 8; ++p) {
        int r = p * 16 + (tid >> 4);
        float4 vv = *(const float4*)(Bf + (n0 + r) * ldb + k0 + (tid & 15) * 4);
        ushort4 hh;
        hh.x = f2h_bits(vv.x); hh.y = f2h_bits(vv.y);
        hh.z = f2h_bits(vv.z); hh.w = f2h_bits(vv.w);
        *(ushort4*)(BsB + r * 128 + (((tid & 15) * 8) ^ ((r & 7) << 4))) = hh;
      }
    }
    __syncthreads();
#pragma unroll
    for (int s = 0; s < 2; ++s) {
      f16x8 af[4], bfr[4];
#pragma unroll
      for (int mi = 0; mi < 4; ++mi) {
        int r = wm * 64 + mi * 16 + cc;
        af[mi] = *(const f16x8*)(AsB + r * 128 + ((s * 64 + 16 * g) ^ ((r & 7) << 4)));
      }
#pragma unroll
      for (int ni = 0; ni < 4; ++ni) {
        int r = wn * 64 + ni * 16 + cc;
        bfr[ni] = *(const f16x8*)(BsB + r * 128 + ((s * 64 + 16 * g) ^ ((r & 7) << 4)));
      }
#pragma unroll
      for (int mi = 0; mi < 4; ++mi)
#pragma unroll
        for (int ni = 0; ni < 4; ++ni)
          acc[mi][ni] = __builtin_amdgcn_mfma_f32_16x16x32_f16(af[mi], bfr[ni], acc[mi][ni], 0, 0, 0);
    }
  }

  float* Cp = C ? C + (long)blockIdx.z * c_bs : nullptr;
  _Float16* Chp = Ch ? Ch + (long)blockIdx.z * ch_bs : nullptr;
#pragma unroll
  for (int ni = 0; ni < 4; ++ni) {
    long col = n0 + wn * 64 + ni * 16 + cc;
    float bcol = (bias && !bias_row) ? bias[col] : 0.0f;
#pragma unroll
    for (int mi = 0; mi < 4; ++mi) {
      long row0 = m0 + wm * 64 + mi * 16 + 4 * g;
#pragma unroll
      for (int rg = 0; rg < 4; ++rg) {
        long row = row0 + rg;
        float b = (bias && bias_row) ? bias[row] : bcol;
        float vv = (acc[mi][ni][rg] + b) * alpha;
        if (Cp) Cp[row * ldc + col] = vv;
        if (Chp) {
          if (cmode == 1) {
            long idx = (((row & 3) * NHEAD + (col >> 7)) * (long)L_SEQ + (row >> 2)) * 128 +
                       (col & 127);
            Chp[idx] = (_Float16)vv;
          } else {
            Chp[row * ldch + col] = (_Float16)vv;
          }
        }
      }
    }
  }
}

// ---------------------------------------------------------------------------
// projqk (R17: BK=64 + XCD-affinity).
// ---------------------------------------------------------------------------
__global__ __launch_bounds__(256) void projqk(
    const _Float16* __restrict__ xh, const _Float16* __restrict__ WqT,
    const _Float16* __restrict__ WkT, const float* __restrict__ bq,
    const float* __restrict__ bk, _Float16* __restrict__ qph,
    _Float16* __restrict__ kph)
{
  __shared__ __align__(16) _Float16 As[64][64];
  __shared__ __align__(16) _Float16 Bs[128][64];
  const int tid = threadIdx.x, lane = tid & 63, wv = tid >> 6;
  const int g = lane >> 4, cc = lane & 15;
  const int wm = wv >> 1, wn = wv & 1;
  const int sel = (int)blockIdx.y;
  const _Float16* A = xh + (long)sel * NQ;
  const _Float16* B = sel ? WkT : WqT;
  const float* bias = sel ? bk : bq;
  const float alpha = sel ? 1.0f : SCALING;
  _Float16* dst = sel ? kph : qph;
  const int bid = (int)blockIdx.x;
  const int j = bid >> 3;
  const int mt = (bid & 7) * 16 + (j & 15);
  const int nt = j >> 4;
  const long m0 = (long)mt * 64;
  const long n0 = (long)nt * 128;

  f32x4 acc[2][4] = {};
  char* AsB = (char*)&As[0][0];
  char* BsB = (char*)&Bs[0][0];

  for (int kt = 0; kt < 16; ++kt) {
    const long k0 = (long)kt << 6;
    __syncthreads();
#pragma unroll
    for (int i = 0; i < 2; ++i) {
      int r = 16 * wv + 8 * i + (lane >> 3);
      int gc = (lane & 7) ^ (r & 7);
      gl_lds16(A + (m0 + r) * 1024 + k0 + gc * 8, &As[16 * wv + 8 * i][0]);
    }
#pragma unroll
    for (int i = 0; i < 4; ++i) {
      int r = 32 * wv + 8 * i + (lane >> 3);
      int gc = (lane & 7) ^ (r & 7);
      gl_lds16(B + (n0 + r) * 1024 + k0 + gc * 8, &Bs[32 * wv + 8 * i][0]);
    }
    __syncthreads();
#pragma unroll
    for (int s = 0; s < 2; ++s) {
      f16x8 af[2], bfr[4];
#pragma unroll
      for (int mi = 0; mi < 2; ++mi) {
        int r = wm * 32 + mi * 16 + cc;
        af[mi] = *(const f16x8*)(AsB + r * 128 + ((s * 64 + 16 * g) ^ ((r & 7) << 4)));
      }
#pragma unroll
      for (int ni = 0; ni < 4; ++ni) {
        int r = wn * 64 + ni * 16 + cc;
        bfr[ni] = *(const f16x8*)(BsB + r * 128 + ((s * 64 + 16 * g) ^ ((r & 7) << 4)));
      }
#pragma unroll
      for (int mi = 0; mi < 2; ++mi)
#pragma unroll
        for (int ni = 0; ni < 4; ++ni)
          acc[mi][ni] = __builtin_amdgcn_mfma_f32_16x16x32_f16(af[mi], bfr[ni], acc[mi][ni], 0, 0, 0);
    }
  }

#pragma unroll
  for (int ni = 0; ni < 4; ++ni) {
    long col = n0 + wn * 64 + ni * 16 + cc;
    float bcol = bias[col];
#pragma unroll
    for (int mi = 0; mi < 2; ++mi) {
      long row0 = m0 + wm * 32 + mi * 16 + 4 * g;
#pragma unroll
      for (int rg = 0; rg < 4; ++rg) {
        long row = row0 + rg;
        float vv = (acc[mi][ni][rg] + bcol) * alpha;
        long idx = (((row & 3) * NHEAD + (col >> 7)) * (long)L_SEQ + (row >> 2)) * 128 +
                   (col & 127);
        dst[idx] = (_Float16)vv;
      }
    }
  }
}

// ---------------------------------------------------------------------------
// proj64 (R19: voT, nc-panel XCD-affinity).
// ---------------------------------------------------------------------------
__global__ __launch_bounds__(256) void proj64(
    const _Float16* __restrict__ Ap, long lda, long a_bs,
    const _Float16* __restrict__ Bp, long ldb, long b_bs,
    _Float16* __restrict__ Ch, long ldch, long ch_bs,
    const float* __restrict__ bias, int bias_row, float alpha, int K,
    int cmode, int ntiles)
{
  __shared__ __align__(16) _Float16 As[64][64];
  __shared__ __align__(16) _Float16 Bs[128][64];
  const int tid = threadIdx.x, lane = tid & 63, wv = tid >> 6;
  const int g = lane >> 4, cc = lane & 15;
  const int wm = wv >> 1, wn = wv & 1;
  const int bid = (int)blockIdx.x;
  const int j = bid >> 3;
  const int nc = (bid & 7) * 2 + (j & 1);
  const int by = j >> 1;
  const long m0 = (long)by * 64;
  const long n0 = (long)nc * 128;
  const _Float16* A = Ap + (long)blockIdx.z * a_bs;
  const _Float16* B = Bp + (long)blockIdx.z * b_bs;
  const int NT = K >> 6;

  f32x4 acc[2][4] = {};
  char* AsB = (char*)&As[0][0];
  char* BsB = (char*)&Bs[0][0];

  for (int kt = 0; kt < NT; ++kt) {
    const long k0 = (long)kt << 6;
    __syncthreads();
#pragma unroll
    for (int i = 0; i < 2; ++i) {
      int r = 16 * wv + 8 * i + (lane >> 3);
      int gc = (lane & 7) ^ (r & 7);
      gl_lds16(A + (m0 + r) * lda + k0 + gc * 8, &As[16 * wv + 8 * i][0]);
    }
#pragma unroll
    for (int i = 0; i < 4; ++i) {
      int r = 32 * wv + 8 * i + (lane >> 3);
      int gc = (lane & 7) ^ (r & 7);
      gl_lds16(B + (n0 + r) * ldb + k0 + gc * 8, &Bs[32 * wv + 8 * i][0]);
    }
    __syncthreads();
#pragma unroll
    for (int s = 0; s < 2; ++s) {
      f16x8 af[2], bfr[4];
#pragma unroll
      for (int mi = 0; mi < 2; ++mi) {
        int r = wm * 32 + mi * 16 + cc;
        af[mi] = *(const f16x8*)(AsB + r * 128 + ((s * 64 + 16 * g) ^ ((r & 7) << 4)));
      }
#pragma unroll
      for (int ni = 0; ni < 4; ++ni) {
        int r = wn * 64 + ni * 16 + cc;
        bfr[ni] = *(const f16x8*)(BsB + r * 128 + ((s * 64 + 16 * g) ^ ((r & 7) << 4)));
      }
#pragma unroll
      for (int mi = 0; mi < 2; ++mi)
#pragma unroll
        for (int ni = 0; ni < 4; ++ni)
          acc[mi][ni] = __builtin_amdgcn_mfma_f32_16x16x32_f16(af[mi], bfr[ni], acc[mi][ni], 0, 0, 0);
    }
  }

  _Float16* Chp = Ch + (long)blockIdx.z * ch_bs;
#pragma unroll
  for (int ni = 0; ni < 4; ++ni) {
    long col = n0 + wn * 64 + ni * 16 + cc;
    float bcol = bias_row ? 0.0f : bias[col];
#pragma unroll
    for (int mi = 0; mi < 2; ++mi) {
      long row0 = m0 + wm * 32 + mi * 16 + 4 * g;
#pragma unroll
      for (int rg = 0; rg < 4; ++rg) {
        long row = row0 + rg;
        float b = bias_row ? bias[row] : bcol;
        float vv = (acc[mi][ni][rg] + b) * alpha;
        if (cmode == 1) {
          long idx = (((row & 3) * NHEAD + (col >> 7)) * (long)L_SEQ + (row >> 2)) * 128 +
                     (col & 127);
          Chp[idx] = (_Float16)vv;
        } else {
          Chp[row * ldch + col] = (_Float16)vv;
        }
      }
    }
  }
}

// ---------------------------------------------------------------------------
// out_gemm16 (R17: BK=128 + XCD-affinity).
// ---------------------------------------------------------------------------
__global__ __launch_bounds__(256) void out_gemm16(
    const _Float16* __restrict__ wm16, const _Float16* __restrict__ voT,
    const float* __restrict__ bo, float* __restrict__ out)
{
  __shared__ __align__(16) _Float16 As[64][128];
  __shared__ __align__(16) _Float16 Bs[128][128];
  const int tid = threadIdx.x, lane = tid & 63, wv = tid >> 6;
  const int g = lane >> 4, cc = lane & 15;
  const int wm = wv >> 1, wn = wv & 1;
  const int bid = (int)blockIdx.x;
  const int j = bid >> 3;
  const int p = (j >> 3) * 8 + (bid & 7);
  const int by = 31 - (p >> 2);
  const int nb = p & 3;
  const int nc = j & 7;
  const long m0 = (long)by * 64;
  const long n0 = (long)nc * 128;
  const _Float16* A = wm16 + (long)nb * L_SEQ * L_SEQ;
  const _Float16* B = voT + (long)nb * 2048L * 1024;
  const int NT = (by + 2) >> 1;
  const int srow = lane >> 4, scl = lane & 15;

  f32x4 acc[2][4] = {};
  char* AsB = (char*)&As[0][0];
  char* BsB = (char*)&Bs[0][0];

  for (int kt = 0; kt < NT; ++kt) {
    const long k0 = (long)kt << 7;
    __syncthreads();
#pragma unroll
    for (int i = 0; i < 4; ++i) {
      int r = 16 * wv + 4 * i + srow;
      int gc = scl ^ (r & 7);
      gl_lds16(A + (m0 + r) * 2048 + k0 + gc * 8, &As[16 * wv + 4 * i][0]);
    }
#pragma unroll
    for (int i = 0; i < 8; ++i) {
      int r = 32 * wv + 4 * i + srow;
      int gc = scl ^ (r & 7);
      gl_lds16(B + (n0 + r) * 2048 + k0 + gc * 8, &Bs[32 * wv + 4 * i][0]);
    }
    __syncthreads();
#pragma unroll
    for (int s = 0; s < 4; ++s) {
      f16x8 af[2], bfr[4];
#pragma unroll
      for (int mi = 0; mi < 2; ++mi) {
        int r = wm * 32 + mi * 16 + cc;
        af[mi] = *(const f16x8*)(AsB + r * 256 + (((4 * s + g) ^ (r & 7)) << 4));
      }
#pragma unroll
      for (int ni = 0; ni < 4; ++ni) {
        int r = wn * 64 + ni * 16 + cc;
        bfr[ni] = *(const f16x8*)(BsB + r * 256 + (((4 * s + g) ^ (r & 7)) << 4));
      }
#pragma unroll
      for (int mi = 0; mi < 2; ++mi)
#pragma unroll
        for (int ni = 0; ni < 4; ++ni)
          acc[mi][ni] = __builtin_amdgcn_mfma_f32_16x16x32_f16(af[mi], bfr[ni], acc[mi][ni], 0, 0, 0);
    }
  }

#pragma unroll
  for (int ni = 0; ni < 4; ++ni) {
    long col = n0 + wn * 64 + ni * 16 + cc;
    float b = bo[col];
#pragma unroll
    for (int mi = 0; mi < 2; ++mi) {
      long l0 = m0 + wm * 32 + mi * 16 + 4 * g;
#pragma unroll
      for (int rg = 0; rg < 4; ++rg)
        out[(l0 + rg) * 4096 + nb * 1024 + col] = acc[mi][ni][rg] + b;
    }
  }
}

// ---------------------------------------------------------------------------
// S1 (R19): K-split partial Zsum, seg-affinity table.
// ---------------------------------------------------------------------------
__global__ __launch_bounds__(256) void s1_kernel(
    const _Float16* __restrict__ qph, const _Float16* __restrict__ kph,
    float* __restrict__ Zsum)
{
  __shared__ __align__(16) _Float16 Qs[64][128];
  __shared__ __align__(16) _Float16 Ks[64][128];
  const int tid = threadIdx.x, lane = tid & 63, w = tid >> 6;
  const int g = lane >> 4, cc = lane & 15;
  const int h = blockIdx.y, nb = blockIdx.z;
  const int bid = (int)blockIdx.x;
  const int val = S1MAP[(bid & 7) * 10 + (bid >> 3)];
  const int by = val & 31, seg = val >> 5;
  const int lb = by * 64;
  const int c0 = seg * 8;
  const int cEnd = min(c0 + 8, by + 1);
  const int srow = lane >> 4, scl = lane & 15;
  const long hb = ((long)(nb * NHEAD + h)) * L_SEQ * 128;
  char* QsB = (char*)&Qs[0][0];
  char* KsB = (char*)&Ks[0][0];

#pragma unroll
  for (int i = 0; i < 4; ++i) {
    int r = 16 * w + 4 * i + srow;
    int gc = scl ^ (r & 7);
    gl_lds16(&qph[hb + (long)(lb + r) * 128 + gc * 8], &Qs[16 * w + 4 * i][0]);
  }
  auto stageK = [&](int ch) {
#pragma unroll
    for (int i = 0; i < 4; ++i) {
      int r = 16 * w + 4 * i + srow;
      int gc = scl ^ (r & 7);
      gl_lds16(&kph[hb + (long)(ch * 64 + r) * 128 + gc * 8], &Ks[16 * w + 4 * i][0]);
    }
  };
  stageK(c0);
  __syncthreads();

  f16x8 qf[4];
  {
    int r = 16 * w + cc;
#pragma unroll
    for (int s = 0; s < 4; ++s)
      qf[s] = *(const f16x8*)(QsB + r * 256 + ((64 * s + 16 * g) ^ ((r & 7) << 4)));
  }

  f32x4 zacc = {0.f, 0.f, 0.f, 0.f};
  const int l0 = lb + 16 * w + 4 * g;
  for (int ch = c0; ch < cEnd; ++ch) {
#pragma unroll
    for (int t = 0; t < 4; ++t) {
      int kr = 16 * t + cc;
      f32x4 acc = {0.f, 0.f, 0.f, 0.f};
#pragma unroll
      for (int s = 0; s < 4; ++s) {
        f16x8 kf = *(const f16x8*)(KsB + kr * 256 + ((64 * s + 16 * g) ^ ((kr & 7) << 4)));
        acc = __builtin_amdgcn_mfma_f32_16x16x32_f16(qf[s], kf, acc, 0, 0, 0);
      }
      int m = ch * 64 + 16 * t + cc;
#pragma unroll
      for (int rg = 0; rg < 4; ++rg) {
        float e = __expf(acc[rg]);
        zacc[rg] += (m <= l0 + rg) ? e : 0.f;
      }
    }
    if (ch + 1 < cEnd) {
      __syncthreads();
      stageK(ch + 1);
      __syncthreads();
    }
  }
#pragma unroll
  for (int rg = 0; rg < 4; ++rg) {
    float vv = zacc[rg];
    vv += __shfl_xor(vv, 1, 16);
    vv += __shfl_xor(vv, 2, 16);
    vv += __shfl_xor(vv, 4, 16);
    vv += __shfl_xor(vv, 8, 16);
    if (cc == 0)
      atomicAdd(&Zsum[((long)nb * NHEAD + h) * L_SEQ + l0 + rg], vv);
  }
}

// ---------------------------------------------------------------------------
// S2 (R18): 64l x 128m tiles + mc-pair XCD-affinity.
// ---------------------------------------------------------------------------
__global__ __launch_bounds__(256) void s2_kernel(
    const _Float16* __restrict__ qph, const _Float16* __restrict__ kph,
    const float* __restrict__ Zsum, float* __restrict__ wmean,
    _Float16* __restrict__ wm16)
{
  __shared__ __align__(16) _Float16 Qs[64][128];
  __shared__ __align__(16) _Float16 Ks[128][128];
  __shared__ float zl[NHEAD][64];
  const int tid = threadIdx.x, lane = tid & 63, w = tid >> 6;
  const int g = lane >> 4, cc = lane & 15;
  const int nb = blockIdx.y;
  const int x = (int)blockIdx.x;
  const int xcd = x & 7, idx = x >> 3;
  const int cnt0 = 32 - 2 * xcd;
  int mc, by;
  if (idx < cnt0) { mc = xcd;      by = 31 - idx; }
  else            { mc = 15 - xcd; by = 31 - (idx - cnt0); }
  const int lb = by * 64, mb = mc * 128;
  const bool diag = (mb + 127 > lb);
  const int srow = lane >> 4, scl = lane & 15;
  char* QsB = (char*)&Qs[0][0];
  char* KsB = (char*)&Ks[0][0];

  for (int i = tid; i < NHEAD * 64; i += 256)
    zl[i >> 6][i & 63] =
        1.0f / (8.0f * Zsum[((long)nb * NHEAD + (i >> 6)) * L_SEQ + lb + (i & 63)]);

  auto stage = [&](int h) {
    const long qb = ((long)(nb * NHEAD + h) * L_SEQ + lb) * 128;
    const long kb = ((long)(nb * NHEAD + h) * L_SEQ + mb) * 128;
#pragma unroll
    for (int i = 0; i < 4; ++i) {
      int r = 16 * w + 4 * i + srow;
      int gc = scl ^ (r & 7);
      gl_lds16(&qph[qb + (long)r * 128 + gc * 8], &Qs[16 * w + 4 * i][0]);
    }
#pragma unroll
    for (int i = 0; i < 8; ++i) {
      int r = 32 * w + 4 * i + srow;
      int gc = scl ^ (r & 7);
      gl_lds16(&kph[kb + (long)r * 128 + gc * 8], &Ks[32 * w + 4 * i][0]);
    }
  };
  stage(0);
  __syncthreads();

  f32x4 wacc[8] = {};
  const int l0 = lb + 16 * w + 4 * g;
  for (int h = 0; h < NHEAD; ++h) {
    f16x8 qf[4];
    int qr = 16 * w + cc;
#pragma unroll
    for (int s = 0; s < 4; ++s)
      qf[s] = *(const f16x8*)(QsB + qr * 256 + ((64 * s + 16 * g) ^ ((qr & 7) << 4)));
    f32x4 zv = *(const f32x4*)&zl[h][16 * w + 4 * g];
#pragma unroll
    for (int t = 0; t < 8; ++t) {
      int kr = 16 * t + cc;
      f32x4 acc = {0.f, 0.f, 0.f, 0.f};
#pragma unroll
      for (int s = 0; s < 4; ++s) {
        f16x8 kf = *(const f16x8*)(KsB + kr * 256 + ((64 * s + 16 * g) ^ ((kr & 7) << 4)));
        acc = __builtin_amdgcn_mfma_f32_16x16x32_f16(qf[s], kf, acc, 0, 0, 0);
      }
      int m = mb + 16 * t + cc;
#pragma unroll
      for (int rg = 0; rg < 4; ++rg) {
        float e = __expf(acc[rg]) * zv[rg];
        wacc[t][rg] += (!diag || m <= l0 + rg) ? e : 0.f;
      }
    }
    if (h + 1 < NHEAD) {
      __syncthreads();
      stage(h + 1);
      __syncthreads();
    }
  }
  float* wout = wmean + (long)nb * L_SEQ * L_SEQ;
  _Float16* w16 = wm16 + (long)nb * L_SEQ * L_SEQ;
#pragma unroll
  for (int t = 0; t < 8; ++t) {
    int m = mb + 16 * t + cc;
#pragma unroll
    for (int rg = 0; rg < 4; ++rg) {
      long idx2 = (long)(l0 + rg) * L_SEQ + m;
      wout[idx2] = wacc[t][rg];
      w16[idx2] = (_Float16)wacc[t][rg];
    }
  }
}

// ---------------------------------------------------------------------------
extern "C" void kernel_launch(void* const* d_in, const int* in_sizes, int n_in,
                              void* d_out, int out_size, void* d_ws, size_t ws_size,
                              hipStream_t stream)
{
  const float* q  = (const float*)d_in[0];
  const float* k  = (const float*)d_in[1];
  const float* v  = (const float*)d_in[2];
  const float* Wq = (const float*)d_in[3];
  const float* bq = (const float*)d_in[4];
  const float* Wk = (const float*)d_in[5];
  const float* bk = (const float*)d_in[6];
  const float* Wv = (const float*)d_in[7];
  const float* bv = (const float*)d_in[8];
  const float* Wo = (const float*)d_in[9];
  const float* bo = (const float*)d_in[10];

  float* out = (float*)d_out;
  float* wmean = out + (long)L_SEQ * NBATCH * DMODEL;

  if (ws_size < (140UL << 20)) return;

  char* ws = (char*)d_ws;
  _Float16* xh   = (_Float16*)(ws);                   // 48 MB (q,k,v f16)
  _Float16* qph  = (_Float16*)(ws + (48L << 20));     // 16 MB head-major
  _Float16* kph  = (_Float16*)(ws + (64L << 20));     // 16 MB head-major
  _Float16* voT  = (_Float16*)(ws + (80L << 20));     // 16 MB
  _Float16* wm16 = (_Float16*)(ws + (96L << 20));     // 33.6 MB (f16 wmean)
  _Float16* WqT  = (_Float16*)(ws + (130L << 20));    // 2 MB
  _Float16* WkT  = (_Float16*)(ws + (132L << 20));    // 2 MB
  _Float16* WoT  = (_Float16*)(ws + (134L << 20));    // 2 MB
  _Float16* WvoT = (_Float16*)(ws + (136L << 20));    // 2 MB
  float*    bvo  = (float*)   (ws + (138L << 20));    // 4 KB
  float*    Zsum = (float*)   (ws + (138L << 20) + (1L << 16));  // 256 KB

  // cvt3 (first) + transposes + parallel bias_proj + zeros, one launch
  prep<<<dim3(32, 32, 17), dim3(32, 8, 1), 0, stream>>>(
      Wq, Wk, Wo, WqT, WkT, WoT, bv, bvo, (float4*)Zsum, wmean, q, k, v, xh);
  gemm16<true, false><<<dim3(8, 8, 1), 256, 0, stream>>>(
      WoT, 1024, 0, Wv, 1024, 0,
      (float*)nullptr, 0, 0, WvoT, 1024, 0,
      (const float*)nullptr, 0, 1.0f, 1024, 0, 0);
  projqk<<<dim3(1024, 2, 1), 256, 0, stream>>>(xh, WqT, WkT, bq, bk, qph, kph);
  proj64<<<dim3(256, 1, 4), 256, 0, stream>>>(
      WvoT, 1024, 0, xh + 2 * NQ, 4096, 1024, voT, 2048, 2048L * 1024,
      bvo, 1, 1.0f, 1024, 0, 16);
  s1_kernel<<<dim3(80, NHEAD, NBATCH), 256, 0, stream>>>(qph, kph, Zsum);
  s2_kernel<<<dim3(272, NBATCH, 1), 256, 0, stream>>>(qph, kph, Zsum, wmean, wm16);
  out_gemm16<<<dim3(1024, 1, 1), 256, 0, stream>>>(wm16, voT, bo, out);
}

// Round 22
// 270.478 us; speedup vs baseline: 1.0973x; 1.0172x over previous
//
#include <hip/hip_runtime.h>

// R22: (1) cvt planes div-free + 16 elems/thread (z<6, which=z>>1; 4x float4
// loads, 2x f16x8 stores — 2x ILP, half the blocks); (2) wmean strict-upper
// zeros moved from prep's tail into out_gemm16's grid (blocks 1024..1503,
// overlapped; zeros are validation-only). Rest = R21 (275.1us best).

#define L_SEQ 2048
#define NBATCH 4
#define DMODEL 1024
#define NHEAD 8
#define SCALING 0.08838834764831845f
#define NQ (2048L * 4 * 1024)

typedef _Float16 f16x8 __attribute__((ext_vector_type(8)));
typedef float f32x4 __attribute__((ext_vector_type(4)));

#define GLOBAL_AS __attribute__((address_space(1)))
#define LDS_AS __attribute__((address_space(3)))

__device__ __forceinline__ unsigned short f2h_bits(float x) {
  _Float16 h = (_Float16)x;
  return __builtin_bit_cast(unsigned short, h);
}

__device__ __forceinline__ void gl_lds16(const void* g, void* l) {
  __builtin_amdgcn_global_load_lds((GLOBAL_AS void*)g, (LDS_AS void*)l, 16, 0, 0);
}

// s1 (by,seg) table: val = seg*32+by; index = (bid&7)*10 + (bid>>3).
__device__ const unsigned char S1MAP[80] = {
    31, 30, 29, 28, 27, 26, 25, 24, 23, 22,
    21, 20, 19, 18, 17, 16, 15, 14, 13, 12,
    11, 10, 9, 8, 7, 6, 5, 4, 3, 2,
    1, 0, 63, 62, 61, 60, 59, 58, 57, 56,
    55, 54, 53, 52, 51, 50, 49, 48, 47, 46,
    45, 44, 43, 42, 41, 40, 95, 94, 93, 92,
    91, 90, 89, 88, 87, 86, 85, 84, 83, 82,
    81, 80, 127, 126, 125, 124, 123, 122, 121, 120
};

// ---------------------------------------------------------------------------
// prep: z=0..5 cvt (16 elems/thread, which=z>>1, no div); z=6..8 weight
// transposes; z=9 parallel bias_proj (y==0) + Zsum zero (y==1,2).
// ---------------------------------------------------------------------------
__global__ __launch_bounds__(256) void prep(
    const float* __restrict__ Wq, const float* __restrict__ Wk,
    const float* __restrict__ Wo,
    _Float16* __restrict__ WqT, _Float16* __restrict__ WkT,
    _Float16* __restrict__ WoT,
    const float* __restrict__ bv, float* __restrict__ bvo,
    float4* __restrict__ Zsum4,
    const float* __restrict__ q, const float* __restrict__ k,
    const float* __restrict__ v, _Float16* __restrict__ xh)
{
  const int z = (int)blockIdx.z;
  const int tid = threadIdx.y * 32 + threadIdx.x;
  if (z < 6) {                               // cvt: xh = f16(q,k,v)
    const int which = z >> 1;
    const float* src = which == 0 ? q : (which == 1 ? k : v);
    long off = ((long)(((z & 1) * 1024 + blockIdx.y * 32 + blockIdx.x) * 256 + tid)) * 16;
    float4 a0 = *(const float4*)(src + off);
    float4 a1 = *(const float4*)(src + off + 4);
    float4 a2 = *(const float4*)(src + off + 8);
    float4 a3 = *(const float4*)(src + off + 12);
    f16x8 h0, h1;
    h0[0] = (_Float16)a0.x; h0[1] = (_Float16)a0.y; h0[2] = (_Float16)a0.z; h0[3] = (_Float16)a0.w;
    h0[4] = (_Float16)a1.x; h0[5] = (_Float16)a1.y; h0[6] = (_Float16)a1.z; h0[7] = (_Float16)a1.w;
    h1[0] = (_Float16)a2.x; h1[1] = (_Float16)a2.y; h1[2] = (_Float16)a2.z; h1[3] = (_Float16)a2.w;
    h1[4] = (_Float16)a3.x; h1[5] = (_Float16)a3.y; h1[6] = (_Float16)a3.z; h1[7] = (_Float16)a3.w;
    _Float16* dst = xh + (long)which * NQ + off;
    *(f16x8*)dst = h0;
    *(f16x8*)(dst + 8) = h1;
    return;
  }
  if (z < 9) {                               // weight transposes
    __shared__ _Float16 tile[32][33];
    const int zz = z - 6;
    const float* in = zz == 0 ? Wq : (zz == 1 ? Wk : Wo);
    _Float16* outp = zz == 0 ? WqT : (zz == 1 ? WkT : WoT);
    int r0 = blockIdx.y * 32, c0 = blockIdx.x * 32;
    for (int i = threadIdx.y; i < 32; i += 8)
      tile[i][threadIdx.x] = (_Float16)in[(long)(r0 + i) * 1024 + c0 + threadIdx.x];
    __syncthreads();
    for (int i = threadIdx.y; i < 32; i += 8)
      outp[(long)(c0 + i) * 1024 + r0 + threadIdx.x] = tile[threadIdx.x][i];
    return;
  }
  // z == 9: parallel bias_proj (y==0) + Zsum zero (y==1,2)
  if (blockIdx.y == 0) {
    if (blockIdx.x < 32) {
      __shared__ float red[8][32];
      const int j = blockIdx.x * 32 + (tid & 31);
      const int i0 = (tid >> 5) * 128;
      float acc = 0.f;
#pragma unroll 4
      for (int i = 0; i < 128; ++i)
        acc += bv[i0 + i] * Wo[(long)(i0 + i) * 1024 + j];
      red[tid >> 5][tid & 31] = acc;
      __syncthreads();
      if (tid < 32) {
        float s = 0.f;
#pragma unroll
        for (int r = 0; r < 8; ++r) s += red[r][tid];
        bvo[blockIdx.x * 32 + tid] = s;
      }
    }
  } else if (blockIdx.y == 1 || blockIdx.y == 2) {
    long idx = ((long)(blockIdx.y - 1) * 32 + blockIdx.x) * 256 + tid;
    if (idx < (long)NBATCH * NHEAD * L_SEQ / 4)
      Zsum4[idx] = (float4){0.f, 0.f, 0.f, 0.f};
  }
}

// ---------------------------------------------------------------------------
// gemm16: 128x128 tile. Retained for the small Wvo prep GEMM only.
// ---------------------------------------------------------------------------
template <bool AF16, bool BF16>
__global__ __launch_bounds__(256) void gemm16(
    const void* __restrict__ Ap, long lda, long a_bs,
    const void* __restrict__ Bp, long ldb, long b_bs,
    float* __restrict__ C, long ldc, long c_bs,
    _Float16* __restrict__ Ch, long ldch, long ch_bs,
    const float* __restrict__ bias, int bias_row, float alpha, int K,
    int causal, int cmode)
{
  __shared__ __align__(16) _Float16 As[128][64];
  __shared__ __align__(16) _Float16 Bs[128][64];
  const int tid = threadIdx.x;
  const int lane = tid & 63, wv = tid >> 6;
  const int g = lane >> 4, cc = lane & 15;
  const int wm = wv >> 1, wn = wv & 1;
  const long m0 = (long)blockIdx.y * 128;
  const long n0 = (long)blockIdx.x * 128;

  const float* Af = nullptr; const _Float16* Ah = nullptr;
  const float* Bf = nullptr; const _Float16* Bh = nullptr;
  if constexpr (AF16) Ah = (const _Float16*)Ap + (long)blockIdx.z * a_bs;
  else                Af = (const float*)Ap + (long)blockIdx.z * a_bs;
  if constexpr (BF16) Bh = (const _Float16*)Bp + (long)blockIdx.z * b_bs;
  else                Bf = (const float*)Bp + (long)blockIdx.z * b_bs;

  int Keff = K;
  if (causal) { int lim = (int)m0 + 128; if (lim < K) Keff = lim; }
  const int NT = Keff >> 6;

  f32x4 acc[4][4] = {};
  char* AsB = (char*)&As[0][0];
  char* BsB = (char*)&Bs[0][0];

  for (int kt = 0; kt < NT; ++kt) {
    const long k0 = (long)kt << 6;
    __syncthreads();
    if constexpr (AF16) {
#pragma unroll
      for (int i = 0; i < 4; ++i) {
        int r = 32 * wv + 8 * i + (lane >> 3);
        int gc = (lane & 7) ^ (r & 7);
        gl_lds16(Ah + (m0 + r) * lda + k0 + gc * 8, &As[32 * wv + 8 * i][0]);
      }
    } else {
#pragma unroll
      for (int p = 0; p < 8; ++p) {
        int r = p * 16 + (tid >> 4);
        float4 vv = *(const float4*)(Af + (m0 + r) * lda + k0 + (tid & 15) * 4);
        ushort4 hh;
        hh.x = f2h_bits(vv.x); hh.y = f2h_bits(vv.y);
        hh.z = f2h_bits(vv.z); hh.w = f2h_bits(vv.w);
        *(ushort4*)(AsB + r * 128 + (((tid & 15) * 8) ^ ((r & 7) << 4))) = hh;
      }
    }
    if constexpr (BF16) {
#pragma unroll
      for (int i = 0; i < 4; ++i) {
        int r = 32 * wv + 8 * i + (lane >> 3);
        int gc = (lane & 7) ^ (r & 7);
        gl_lds16(Bh + (n0 + r) * ldb + k0 + gc * 8, &Bs[32 * wv + 8 * i][0]);
      }
    } else {
#pragma unroll
      for (int p = 0; p < 8; ++p) {
        int r = p * 16 + (tid >> 4);
        float4 vv = *(const float4*)(Bf + (n0 + r) * ldb + k0 + (tid & 15) * 4);
        ushort4 hh;
        hh.x = f2h_bits(vv.x); hh.y = f2h_bits(vv.y);
        hh.z = f2h_bits(vv.z); hh.w = f2h_bits(vv.w);
        *(ushort4*)(BsB + r * 128 + (((tid & 15) * 8) ^ ((r & 7) << 4))) = hh;
      }
    }
    __syncthreads();
#pragma unroll
    for (int s = 0; s < 2; ++s) {
      f16x8 af[4], bfr[4];
#pragma unroll
      for (int mi = 0; mi < 4; ++mi) {
        int r = wm * 64 + mi * 16 + cc;
        af[mi] = *(const f16x8*)(AsB + r * 128 + ((s * 64 + 16 * g) ^ ((r & 7) << 4)));
      }
#pragma unroll
      for (int ni = 0; ni < 4; ++ni) {
        int r = wn * 64 + ni * 16 + cc;
        bfr[ni] = *(const f16x8*)(BsB + r * 128 + ((s * 64 + 16 * g) ^ ((r & 7) << 4)));
      }
#pragma unroll
      for (int mi = 0; mi < 4; ++mi)
#pragma unroll
        for (int ni = 0; ni < 4; ++ni)
          acc[mi][ni] = __builtin_amdgcn_mfma_f32_16x16x32_f16(af[mi], bfr[ni], acc[mi][ni], 0, 0, 0);
    }
  }

  float* Cp = C ? C + (long)blockIdx.z * c_bs : nullptr;
  _Float16* Chp = Ch ? Ch + (long)blockIdx.z * ch_bs : nullptr;
#pragma unroll
  for (int ni = 0; ni < 4; ++ni) {
    long col = n0 + wn * 64 + ni * 16 + cc;
    float bcol = (bias && !bias_row) ? bias[col] : 0.0f;
#pragma unroll
    for (int mi = 0; mi < 4; ++mi) {
      long row0 = m0 + wm * 64 + mi * 16 + 4 * g;
#pragma unroll
      for (int rg = 0; rg < 4; ++rg) {
        long row = row0 + rg;
        float b = (bias && bias_row) ? bias[row] : bcol;
        float vv = (acc[mi][ni][rg] + b) * alpha;
        if (Cp) Cp[row * ldc + col] = vv;
        if (Chp) {
          if (cmode == 1) {
            long idx = (((row & 3) * NHEAD + (col >> 7)) * (long)L_SEQ + (row >> 2)) * 128 +
                       (col & 127);
            Chp[idx] = (_Float16)vv;
          } else {
            Chp[row * ldch + col] = (_Float16)vv;
          }
        }
      }
    }
  }
}

// ---------------------------------------------------------------------------
// projqk (R17: BK=64 + XCD-affinity).
// ---------------------------------------------------------------------------
__global__ __launch_bounds__(256) void projqk(
    const _Float16* __restrict__ xh, const _Float16* __restrict__ WqT,
    const _Float16* __restrict__ WkT, const float* __restrict__ bq,
    const float* __restrict__ bk, _Float16* __restrict__ qph,
    _Float16* __restrict__ kph)
{
  __shared__ __align__(16) _Float16 As[64][64];
  __shared__ __align__(16) _Float16 Bs[128][64];
  const int tid = threadIdx.x, lane = tid & 63, wv = tid >> 6;
  const int g = lane >> 4, cc = lane & 15;
  const int wm = wv >> 1, wn = wv & 1;
  const int sel = (int)blockIdx.y;
  const _Float16* A = xh + (long)sel * NQ;
  const _Float16* B = sel ? WkT : WqT;
  const float* bias = sel ? bk : bq;
  const float alpha = sel ? 1.0f : SCALING;
  _Float16* dst = sel ? kph : qph;
  const int bid = (int)blockIdx.x;
  const int j = bid >> 3;
  const int mt = (bid & 7) * 16 + (j & 15);
  const int nt = j >> 4;
  const long m0 = (long)mt * 64;
  const long n0 = (long)nt * 128;

  f32x4 acc[2][4] = {};
  char* AsB = (char*)&As[0][0];
  char* BsB = (char*)&Bs[0][0];

  for (int kt = 0; kt < 16; ++kt) {
    const long k0 = (long)kt << 6;
    __syncthreads();
#pragma unroll
    for (int i = 0; i < 2; ++i) {
      int r = 16 * wv + 8 * i + (lane >> 3);
      int gc = (lane & 7) ^ (r & 7);
      gl_lds16(A + (m0 + r) * 1024 + k0 + gc * 8, &As[16 * wv + 8 * i][0]);
    }
#pragma unroll
    for (int i = 0; i < 4; ++i) {
      int r = 32 * wv + 8 * i + (lane >> 3);
      int gc = (lane & 7) ^ (r & 7);
      gl_lds16(B + (n0 + r) * 1024 + k0 + gc * 8, &Bs[32 * wv + 8 * i][0]);
    }
    __syncthreads();
#pragma unroll
    for (int s = 0; s < 2; ++s) {
      f16x8 af[2], bfr[4];
#pragma unroll
      for (int mi = 0; mi < 2; ++mi) {
        int r = wm * 32 + mi * 16 + cc;
        af[mi] = *(const f16x8*)(AsB + r * 128 + ((s * 64 + 16 * g) ^ ((r & 7) << 4)));
      }
#pragma unroll
      for (int ni = 0; ni < 4; ++ni) {
        int r = wn * 64 + ni * 16 + cc;
        bfr[ni] = *(const f16x8*)(BsB + r * 128 + ((s * 64 + 16 * g) ^ ((r & 7) << 4)));
      }
#pragma unroll
      for (int mi = 0; mi < 2; ++mi)
#pragma unroll
        for (int ni = 0; ni < 4; ++ni)
          acc[mi][ni] = __builtin_amdgcn_mfma_f32_16x16x32_f16(af[mi], bfr[ni], acc[mi][ni], 0, 0, 0);
    }
  }

#pragma unroll
  for (int ni = 0; ni < 4; ++ni) {
    long col = n0 + wn * 64 + ni * 16 + cc;
    float bcol = bias[col];
#pragma unroll
    for (int mi = 0; mi < 2; ++mi) {
      long row0 = m0 + wm * 32 + mi * 16 + 4 * g;
#pragma unroll
      for (int rg = 0; rg < 4; ++rg) {
        long row = row0 + rg;
        float vv = (acc[mi][ni][rg] + bcol) * alpha;
        long idx = (((row & 3) * NHEAD + (col >> 7)) * (long)L_SEQ + (row >> 2)) * 128 +
                   (col & 127);
        dst[idx] = (_Float16)vv;
      }
    }
  }
}

// ---------------------------------------------------------------------------
// proj64 (R19: voT, nc-panel XCD-affinity).
// ---------------------------------------------------------------------------
__global__ __launch_bounds__(256) void proj64(
    const _Float16* __restrict__ Ap, long lda, long a_bs,
    const _Float16* __restrict__ Bp, long ldb, long b_bs,
    _Float16* __restrict__ Ch, long ldch, long ch_bs,
    const float* __restrict__ bias, int bias_row, float alpha, int K,
    int cmode, int ntiles)
{
  __shared__ __align__(16) _Float16 As[64][64];
  __shared__ __align__(16) _Float16 Bs[128][64];
  const int tid = threadIdx.x, lane = tid & 63, wv = tid >> 6;
  const int g = lane >> 4, cc = lane & 15;
  const int wm = wv >> 1, wn = wv & 1;
  const int bid = (int)blockIdx.x;
  const int j = bid >> 3;
  const int nc = (bid & 7) * 2 + (j & 1);
  const int by = j >> 1;
  const long m0 = (long)by * 64;
  const long n0 = (long)nc * 128;
  const _Float16* A = Ap + (long)blockIdx.z * a_bs;
  const _Float16* B = Bp + (long)blockIdx.z * b_bs;
  const int NT = K >> 6;

  f32x4 acc[2][4] = {};
  char* AsB = (char*)&As[0][0];
  char* BsB = (char*)&Bs[0][0];

  for (int kt = 0; kt < NT; ++kt) {
    const long k0 = (long)kt << 6;
    __syncthreads();
#pragma unroll
    for (int i = 0; i < 2; ++i) {
      int r = 16 * wv + 8 * i + (lane >> 3);
      int gc = (lane & 7) ^ (r & 7);
      gl_lds16(A + (m0 + r) * lda + k0 + gc * 8, &As[16 * wv + 8 * i][0]);
    }
#pragma unroll
    for (int i = 0; i < 4; ++i) {
      int r = 32 * wv + 8 * i + (lane >> 3);
      int gc = (lane & 7) ^ (r & 7);
      gl_lds16(B + (n0 + r) * ldb + k0 + gc * 8, &Bs[32 * wv + 8 * i][0]);
    }
    __syncthreads();
#pragma unroll
    for (int s = 0; s < 2; ++s) {
      f16x8 af[2], bfr[4];
#pragma unroll
      for (int mi = 0; mi < 2; ++mi) {
        int r = wm * 32 + mi * 16 + cc;
        af[mi] = *(const f16x8*)(AsB + r * 128 + ((s * 64 + 16 * g) ^ ((r & 7) << 4)));
      }
#pragma unroll
      for (int ni = 0; ni < 4; ++ni) {
        int r = wn * 64 + ni * 16 + cc;
        bfr[ni] = *(const f16x8*)(BsB + r * 128 + ((s * 64 + 16 * g) ^ ((r & 7) << 4)));
      }
#pragma unroll
      for (int mi = 0; mi < 2; ++mi)
#pragma unroll
        for (int ni = 0; ni < 4; ++ni)
          acc[mi][ni] = __builtin_amdgcn_mfma_f32_16x16x32_f16(af[mi], bfr[ni], acc[mi][ni], 0, 0, 0);
    }
  }

  _Float16* Chp = Ch + (long)blockIdx.z * ch_bs;
#pragma unroll
  for (int ni = 0; ni < 4; ++ni) {
    long col = n0 + wn * 64 + ni * 16 + cc;
    float bcol = bias_row ? 0.0f : bias[col];
#pragma unroll
    for (int mi = 0; mi < 2; ++mi) {
      long row0 = m0 + wm * 32 + mi * 16 + 4 * g;
#pragma unroll
      for (int rg = 0; rg < 4; ++rg) {
        long row = row0 + rg;
        float b = bias_row ? bias[row] : bcol;
        float vv = (acc[mi][ni][rg] + b) * alpha;
        if (cmode == 1) {
          long idx = (((row & 3) * NHEAD + (col >> 7)) * (long)L_SEQ + (row >> 2)) * 128 +
                     (col & 127);
          Chp[idx] = (_Float16)vv;
        } else {
          Chp[row * ldch + col] = (_Float16)vv;
        }
      }
    }
  }
}

// ---------------------------------------------------------------------------
// out_gemm16 (R17 + fused wmean-zeros): blocks 0..1023 = causal out-GEMM
// (BK=128, XCD-affinity); blocks 1024..1503 write the strict-upper wmean
// zeros (validation-only region; overlaps the GEMM).
// ---------------------------------------------------------------------------
__global__ __launch_bounds__(256) void out_gemm16(
    const _Float16* __restrict__ wm16, const _Float16* __restrict__ voT,
    const float* __restrict__ bo, float* __restrict__ out,
    float* __restrict__ wmean)
{
  const int tid = threadIdx.x;
  const int bid = (int)blockIdx.x;
  if (bid >= 1024) {                         // wmean strict-upper zeros
    int i = bid - 1024;
    int t = i % 120, nb = i / 120;
    int by = 0, rem = t;
    while (rem >= 15 - by) { rem -= 15 - by; ++by; }
    const int mc = by + 1 + rem;
    const int tr = tid >> 1, th = tid & 1;
    float4 z4 = {0.f, 0.f, 0.f, 0.f};
    float* p = wmean + (long)nb * L_SEQ * L_SEQ + (long)(by * 128 + tr) * L_SEQ +
               mc * 128 + th * 64;
#pragma unroll
    for (int jj = 0; jj < 16; ++jj) ((float4*)p)[jj] = z4;
    return;
  }
  __shared__ __align__(16) _Float16 As[64][128];
  __shared__ __align__(16) _Float16 Bs[128][128];
  const int lane = tid & 63, wv = tid >> 6;
  const int g = lane >> 4, cc = lane & 15;
  const int wm = wv >> 1, wn = wv & 1;
  const int j = bid >> 3;
  const int p = (j >> 3) * 8 + (bid & 7);
  const int by = 31 - (p >> 2);
  const int nb = p & 3;
  const int nc = j & 7;
  const long m0 = (long)by * 64;
  const long n0 = (long)nc * 128;
  const _Float16* A = wm16 + (long)nb * L_SEQ * L_SEQ;
  const _Float16* B = voT + (long)nb * 2048L * 1024;
  const int NT = (by + 2) >> 1;
  const int srow = lane >> 4, scl = lane & 15;

  f32x4 acc[2][4] = {};
  char* AsB = (char*)&As[0][0];
  char* BsB = (char*)&Bs[0][0];

  for (int kt = 0; kt < NT; ++kt) {
    const long k0 = (long)kt << 7;
    __syncthreads();
#pragma unroll
    for (int i = 0; i < 4; ++i) {
      int r = 16 * wv + 4 * i + srow;
      int gc = scl ^ (r & 7);
      gl_lds16(A + (m0 + r) * 2048 + k0 + gc * 8, &As[16 * wv + 4 * i][0]);
    }
#pragma unroll
    for (int i = 0; i < 8; ++i) {
      int r = 32 * wv + 4 * i + srow;
      int gc = scl ^ (r & 7);
      gl_lds16(B + (n0 + r) * 2048 + k0 + gc * 8, &Bs[32 * wv + 4 * i][0]);
    }
    __syncthreads();
#pragma unroll
    for (int s = 0; s < 4; ++s) {
      f16x8 af[2], bfr[4];
#pragma unroll
      for (int mi = 0; mi < 2; ++mi) {
        int r = wm * 32 + mi * 16 + cc;
        af[mi] = *(const f16x8*)(AsB + r * 256 + (((4 * s + g) ^ (r & 7)) << 4));
      }
#pragma unroll
      for (int ni = 0; ni < 4; ++ni) {
        int r = wn * 64 + ni * 16 + cc;
        bfr[ni] = *(const f16x8*)(BsB + r * 256 + (((4 * s + g) ^ (r & 7)) << 4));
      }
#pragma unroll
      for (int mi = 0; mi < 2; ++mi)
#pragma unroll
        for (int ni = 0; ni < 4; ++ni)
          acc[mi][ni] = __builtin_amdgcn_mfma_f32_16x16x32_f16(af[mi], bfr[ni], acc[mi][ni], 0, 0, 0);
    }
  }

#pragma unroll
  for (int ni = 0; ni < 4; ++ni) {
    long col = n0 + wn * 64 + ni * 16 + cc;
    float b = bo[col];
#pragma unroll
    for (int mi = 0; mi < 2; ++mi) {
      long l0 = m0 + wm * 32 + mi * 16 + 4 * g;
#pragma unroll
      for (int rg = 0; rg < 4; ++rg)
        out[(l0 + rg) * 4096 + nb * 1024 + col] = acc[mi][ni][rg] + b;
    }
  }
}

// ---------------------------------------------------------------------------
// S1 (R19): K-split partial Zsum, seg-affinity table.
// ---------------------------------------------------------------------------
__global__ __launch_bounds__(256) void s1_kernel(
    const _Float16* __restrict__ qph, const _Float16* __restrict__ kph,
    float* __restrict__ Zsum)
{
  __shared__ __align__(16) _Float16 Qs[64][128];
  __shared__ __align__(16) _Float16 Ks[64][128];
  const int tid = threadIdx.x, lane = tid & 63, w = tid >> 6;
  const int g = lane >> 4, cc = lane & 15;
  const int h = blockIdx.y, nb = blockIdx.z;
  const int bid = (int)blockIdx.x;
  const int val = S1MAP[(bid & 7) * 10 + (bid >> 3)];
  const int by = val & 31, seg = val >> 5;
  const int lb = by * 64;
  const int c0 = seg * 8;
  const int cEnd = min(c0 + 8, by + 1);
  const int srow = lane >> 4, scl = lane & 15;
  const long hb = ((long)(nb * NHEAD + h)) * L_SEQ * 128;
  char* QsB = (char*)&Qs[0][0];
  char* KsB = (char*)&Ks[0][0];

#pragma unroll
  for (int i = 0; i < 4; ++i) {
    int r = 16 * w + 4 * i + srow;
    int gc = scl ^ (r & 7);
    gl_lds16(&qph[hb + (long)(lb + r) * 128 + gc * 8], &Qs[16 * w + 4 * i][0]);
  }
  auto stageK = [&](int ch) {
#pragma unroll
    for (int i = 0; i < 4; ++i) {
      int r = 16 * w + 4 * i + srow;
      int gc = scl ^ (r & 7);
      gl_lds16(&kph[hb + (long)(ch * 64 + r) * 128 + gc * 8], &Ks[16 * w + 4 * i][0]);
    }
  };
  stageK(c0);
  __syncthreads();

  f16x8 qf[4];
  {
    int r = 16 * w + cc;
#pragma unroll
    for (int s = 0; s < 4; ++s)
      qf[s] = *(const f16x8*)(QsB + r * 256 + ((64 * s + 16 * g) ^ ((r & 7) << 4)));
  }

  f32x4 zacc = {0.f, 0.f, 0.f, 0.f};
  const int l0 = lb + 16 * w + 4 * g;
  for (int ch = c0; ch < cEnd; ++ch) {
#pragma unroll
    for (int t = 0; t < 4; ++t) {
      int kr = 16 * t + cc;
      f32x4 acc = {0.f, 0.f, 0.f, 0.f};
#pragma unroll
      for (int s = 0; s < 4; ++s) {
        f16x8 kf = *(const f16x8*)(KsB + kr * 256 + ((64 * s + 16 * g) ^ ((kr & 7) << 4)));
        acc = __builtin_amdgcn_mfma_f32_16x16x32_f16(qf[s], kf, acc, 0, 0, 0);
      }
      int m = ch * 64 + 16 * t + cc;
#pragma unroll
      for (int rg = 0; rg < 4; ++rg) {
        float e = __expf(acc[rg]);
        zacc[rg] += (m <= l0 + rg) ? e : 0.f;
      }
    }
    if (ch + 1 < cEnd) {
      __syncthreads();
      stageK(ch + 1);
      __syncthreads();
    }
  }
#pragma unroll
  for (int rg = 0; rg < 4; ++rg) {
    float vv = zacc[rg];
    vv += __shfl_xor(vv, 1, 16);
    vv += __shfl_xor(vv, 2, 16);
    vv += __shfl_xor(vv, 4, 16);
    vv += __shfl_xor(vv, 8, 16);
    if (cc == 0)
      atomicAdd(&Zsum[((long)nb * NHEAD + h) * L_SEQ + l0 + rg], vv);
  }
}

// ---------------------------------------------------------------------------
// S2 (R18): 64l x 128m tiles + mc-pair XCD-affinity.
// ---------------------------------------------------------------------------
__global__ __launch_bounds__(256) void s2_kernel(
    const _Float16* __restrict__ qph, const _Float16* __restrict__ kph,
    const float* __restrict__ Zsum, float* __restrict__ wmean,
    _Float16* __restrict__ wm16)
{
  __shared__ __align__(16) _Float16 Qs[64][128];
  __shared__ __align__(16) _Float16 Ks[128][128];
  __shared__ float zl[NHEAD][64];
  const int tid = threadIdx.x, lane = tid & 63, w = tid >> 6;
  const int g = lane >> 4, cc = lane & 15;
  const int nb = blockIdx.y;
  const int x = (int)blockIdx.x;
  const int xcd = x & 7, idx = x >> 3;
  const int cnt0 = 32 - 2 * xcd;
  int mc, by;
  if (idx < cnt0) { mc = xcd;      by = 31 - idx; }
  else            { mc = 15 - xcd; by = 31 - (idx - cnt0); }
  const int lb = by * 64, mb = mc * 128;
  const bool diag = (mb + 127 > lb);
  const int srow = lane >> 4, scl = lane & 15;
  char* QsB = (char*)&Qs[0][0];
  char* KsB = (char*)&Ks[0][0];

  for (int i = tid; i < NHEAD * 64; i += 256)
    zl[i >> 6][i & 63] =
        1.0f / (8.0f * Zsum[((long)nb * NHEAD + (i >> 6)) * L_SEQ + lb + (i & 63)]);

  auto stage = [&](int h) {
    const long qb = ((long)(nb * NHEAD + h) * L_SEQ + lb) * 128;
    const long kb = ((long)(nb * NHEAD + h) * L_SEQ + mb) * 128;
#pragma unroll
    for (int i = 0; i < 4; ++i) {
      int r = 16 * w + 4 * i + srow;
      int gc = scl ^ (r & 7);
      gl_lds16(&qph[qb + (long)r * 128 + gc * 8], &Qs[16 * w + 4 * i][0]);
    }
#pragma unroll
    for (int i = 0; i < 8; ++i) {
      int r = 32 * w + 4 * i + srow;
      int gc = scl ^ (r & 7);
      gl_lds16(&kph[kb + (long)r * 128 + gc * 8], &Ks[32 * w + 4 * i][0]);
    }
  };
  stage(0);
  __syncthreads();

  f32x4 wacc[8] = {};
  const int l0 = lb + 16 * w + 4 * g;
  for (int h = 0; h < NHEAD; ++h) {
    f16x8 qf[4];
    int qr = 16 * w + cc;
#pragma unroll
    for (int s = 0; s < 4; ++s)
      qf[s] = *(const f16x8*)(QsB + qr * 256 + ((64 * s + 16 * g) ^ ((qr & 7) << 4)));
    f32x4 zv = *(const f32x4*)&zl[h][16 * w + 4 * g];
#pragma unroll
    for (int t = 0; t < 8; ++t) {
      int kr = 16 * t + cc;
      f32x4 acc = {0.f, 0.f, 0.f, 0.f};
#pragma unroll
      for (int s = 0; s < 4; ++s) {
        f16x8 kf = *(const f16x8*)(KsB + kr * 256 + ((64 * s + 16 * g) ^ ((kr & 7) << 4)));
        acc = __builtin_amdgcn_mfma_f32_16x16x32_f16(qf[s], kf, acc, 0, 0, 0);
      }
      int m = mb + 16 * t + cc;
#pragma unroll
      for (int rg = 0; rg < 4; ++rg) {
        float e = __expf(acc[rg]) * zv[rg];
        wacc[t][rg] += (!diag || m <= l0 + rg) ? e : 0.f;
      }
    }
    if (h + 1 < NHEAD) {
      __syncthreads();
      stage(h + 1);
      __syncthreads();
    }
  }
  float* wout = wmean + (long)nb * L_SEQ * L_SEQ;
  _Float16* w16 = wm16 + (long)nb * L_SEQ * L_SEQ;
#pragma unroll
  for (int t = 0; t < 8; ++t) {
    int m = mb + 16 * t + cc;
#pragma unroll
    for (int rg = 0; rg < 4; ++rg) {
      long idx2 = (long)(l0 + rg) * L_SEQ + m;
      wout[idx2] = wacc[t][rg];
      w16[idx2] = (_Float16)wacc[t][rg];
    }
  }
}

// ---------------------------------------------------------------------------
extern "C" void kernel_launch(void* const* d_in, const int* in_sizes, int n_in,
                              void* d_out, int out_size, void* d_ws, size_t ws_size,
                              hipStream_t stream)
{
  const float* q  = (const float*)d_in[0];
  const float* k  = (const float*)d_in[1];
  const float* v  = (const float*)d_in[2];
  const float* Wq = (const float*)d_in[3];
  const float* bq = (const float*)d_in[4];
  const float* Wk = (const float*)d_in[5];
  const float* bk = (const float*)d_in[6];
  const float* Wv = (const float*)d_in[7];
  const float* bv = (const float*)d_in[8];
  const float* Wo = (const float*)d_in[9];
  const float* bo = (const float*)d_in[10];

  float* out = (float*)d_out;
  float* wmean = out + (long)L_SEQ * NBATCH * DMODEL;

  if (ws_size < (140UL << 20)) return;

  char* ws = (char*)d_ws;
  _Float16* xh   = (_Float16*)(ws);                   // 48 MB (q,k,v f16)
  _Float16* qph  = (_Float16*)(ws + (48L << 20));     // 16 MB head-major
  _Float16* kph  = (_Float16*)(ws + (64L << 20));     // 16 MB head-major
  _Float16* voT  = (_Float16*)(ws + (80L << 20));     // 16 MB
  _Float16* wm16 = (_Float16*)(ws + (96L << 20));     // 33.6 MB (f16 wmean)
  _Float16* WqT  = (_Float16*)(ws + (130L << 20));    // 2 MB
  _Float16* WkT  = (_Float16*)(ws + (132L << 20));    // 2 MB
  _Float16* WoT  = (_Float16*)(ws + (134L << 20));    // 2 MB
  _Float16* WvoT = (_Float16*)(ws + (136L << 20));    // 2 MB
  float*    bvo  = (float*)   (ws + (138L << 20));    // 4 KB
  float*    Zsum = (float*)   (ws + (138L << 20) + (1L << 16));  // 256 KB

  // cvt (div-free, 16/thread) + transposes + bias_proj + Zsum zero
  prep<<<dim3(32, 32, 10), dim3(32, 8, 1), 0, stream>>>(
      Wq, Wk, Wo, WqT, WkT, WoT, bv, bvo, (float4*)Zsum, q, k, v, xh);
  gemm16<true, false><<<dim3(8, 8, 1), 256, 0, stream>>>(
      WoT, 1024, 0, Wv, 1024, 0,
      (float*)nullptr, 0, 0, WvoT, 1024, 0,
      (const float*)nullptr, 0, 1.0f, 1024, 0, 0);
  projqk<<<dim3(1024, 2, 1), 256, 0, stream>>>(xh, WqT, WkT, bq, bk, qph, kph);
  proj64<<<dim3(256, 1, 4), 256, 0, stream>>>(
      WvoT, 1024, 0, xh + 2 * NQ, 4096, 1024, voT, 2048, 2048L * 1024,
      bvo, 1, 1.0f, 1024, 0, 16);
  s1_kernel<<<dim3(80, NHEAD, NBATCH), 256, 0, stream>>>(qph, kph, Zsum);
  s2_kernel<<<dim3(272, NBATCH, 1), 256, 0, stream>>>(qph, kph, Zsum, wmean, wm16);
  // out-GEMM + fused wmean strict-upper zeros (blocks 1024..1503)
  out_gemm16<<<dim3(1504, 1, 1), 256, 0, stream>>>(wm16, voT, bo, out, wmean);
}